// Round 1
// baseline (1799.497 us; speedup 1.0000x reference)
//
#include <hip/hip_runtime.h>
#include <math.h>

#define KORD 3
#ifndef M_PI
#define M_PI 3.14159265358979323846
#endif

__device__ __forceinline__ float leaky_(float v){ return v >= 0.f ? v : 0.01f*v; }

// ---------------- Chebyshev coefficients from temp ----------------
__global__ void k_coe(const float* __restrict__ temp, float* __restrict__ coe){
  if (threadIdx.x == 0 && blockIdx.x == 0){
    for (int i = 0; i <= KORD; ++i){
      float acc = 0.f;
      for (int j = 0; j <= KORD; ++j){
        double th = ((double)(KORD - j) + 0.5) * M_PI / (double)(KORD + 1);
        float t = temp[j]; t = t > 0.f ? t : 0.f;
        acc += t * (float)cos((double)i * th);
      }
      coe[i] = acc * (2.f / (float)(KORD + 1));
    }
  }
}

// ---------------- h = x[...,None]*Wp + bp ----------------
// x: chunk base (CH*512), H: CH*512*64
__global__ __launch_bounds__(256) void k_embed(const float* __restrict__ x,
    const float* __restrict__ Wp, const float* __restrict__ bp,
    float* __restrict__ H){
  int idx = blockIdx.x*256 + threadIdx.x;
  int d  = idx & 63;
  int n  = (idx >> 6) & 511;
  int cs = idx >> 15;
  H[idx] = x[cs*512 + n]*Wp[d] + bp[d];
}

// ---------------- Generic GEMM: Y[cs] = A[cs] @ X[cs] (K=512) ----------------
// A row-major [512][512] (aStride=0 => shared). X row-major [512][XW].
// EPI==0: Y = acc ; EPI==1: Y = 2*acc - Z  (Chebyshev step)
template<int CT, int EPI>
__global__ __launch_bounds__(256) void k_gemm(
    const float* __restrict__ A, size_t aStride,
    const float* __restrict__ X, size_t xStride,
    const float* __restrict__ Z, size_t zStride,
    float* __restrict__ Y, size_t yStride){
  constexpr int XW = CT*64;
  __shared__ float AsT[64][68];
  __shared__ float Xs[64][68];
  const int rt = blockIdx.x, ct = blockIdx.y, cs = blockIdx.z;
  const float* Ab = A + (size_t)cs*aStride;
  const float* Xb = X + (size_t)cs*xStride;
  const int tid = threadIdx.x, tx = tid & 15, ty = tid >> 4;
  const int n0 = rt*64, c0 = ct*64;
  float acc[4][4] = {};
  for (int k0 = 0; k0 < 512; k0 += 64){
    __syncthreads();
#pragma unroll
    for (int p = 0; p < 16; ++p){
      int q = p*256 + tid;
      int r = q >> 6, c = q & 63;
      AsT[c][r] = Ab[(size_t)(n0 + r)*512 + (k0 + c)];
      Xs[r][c]  = Xb[(size_t)(k0 + r)*XW  + (c0 + c)];
    }
    __syncthreads();
#pragma unroll 8
    for (int kk = 0; kk < 64; ++kk){
      const float4 a4 = *(const float4*)&AsT[kk][ty*4];
      const float4 b4 = *(const float4*)&Xs[kk][tx*4];
      const float av[4] = {a4.x, a4.y, a4.z, a4.w};
      const float bv[4] = {b4.x, b4.y, b4.z, b4.w};
#pragma unroll
      for (int i = 0; i < 4; ++i)
#pragma unroll
        for (int j = 0; j < 4; ++j) acc[i][j] += av[i]*bv[j];
    }
  }
#pragma unroll
  for (int i = 0; i < 4; ++i){
    int n = n0 + ty*4 + i;
#pragma unroll
    for (int j = 0; j < 4; ++j){
      int c = c0 + tx*4 + j;
      float v = acc[i][j];
      if (EPI == 1) v = 2.f*v - Z[(size_t)cs*zStride + (size_t)n*XW + c];
      Y[(size_t)cs*yStride + (size_t)n*XW + c] = v;
    }
  }
}

// ---------------- P = tanh(H @ KX^T + bsa)  (K=64) ----------------
__global__ __launch_bounds__(256) void k_prod(
    const float* __restrict__ H, const float* __restrict__ KX,
    const float* __restrict__ bsa, float* __restrict__ P){
  __shared__ float HsT[64][68];
  __shared__ float KsT[64][68];
  const int nt = blockIdx.x, mt = blockIdx.y, cs = blockIdx.z;
  const float* Hb = H  + (size_t)cs*32768;
  const float* Kb = KX + (size_t)cs*32768;
  const int tid = threadIdx.x, tx = tid & 15, ty = tid >> 4;
#pragma unroll
  for (int p = 0; p < 16; ++p){
    int q = p*256 + tid;
    int r = q >> 6, d = q & 63;
    HsT[d][r] = Hb[(size_t)(nt*64 + r)*64 + d];
    KsT[d][r] = Kb[(size_t)(mt*64 + r)*64 + d];
  }
  __syncthreads();
  float acc[4][4] = {};
#pragma unroll 8
  for (int kk = 0; kk < 64; ++kk){
    const float4 a4 = *(const float4*)&HsT[kk][ty*4];
    const float4 b4 = *(const float4*)&KsT[kk][tx*4];
    const float av[4] = {a4.x, a4.y, a4.z, a4.w};
    const float bv[4] = {b4.x, b4.y, b4.z, b4.w};
#pragma unroll
    for (int i = 0; i < 4; ++i)
#pragma unroll
      for (int j = 0; j < 4; ++j) acc[i][j] += av[i]*bv[j];
  }
#pragma unroll
  for (int i = 0; i < 4; ++i){
    int n = nt*64 + ty*4 + i;
#pragma unroll
    for (int j = 0; j < 4; ++j){
      int m = mt*64 + tx*4 + j;
      P[(size_t)cs*262144 + (size_t)n*512 + m] =
          tanhf(acc[i][j] + bsa[(size_t)n*512 + m]);
    }
  }
}

// ---------------- row softmax over last dim (512), in place ----------------
__global__ __launch_bounds__(256) void k_softmax(float* __restrict__ S){
  int row  = blockIdx.x*4 + (threadIdx.x >> 6);
  int lane = threadIdx.x & 63;
  float* p = S + (size_t)row*512;
  float4 v0 = ((float4*)p)[lane*2];
  float4 v1 = ((float4*)p)[lane*2 + 1];
  float mx = fmaxf(fmaxf(fmaxf(v0.x, v0.y), fmaxf(v0.z, v0.w)),
                   fmaxf(fmaxf(v1.x, v1.y), fmaxf(v1.z, v1.w)));
#pragma unroll
  for (int m = 1; m < 64; m <<= 1) mx = fmaxf(mx, __shfl_xor(mx, m, 64));
  v0.x = expf(v0.x - mx); v0.y = expf(v0.y - mx);
  v0.z = expf(v0.z - mx); v0.w = expf(v0.w - mx);
  v1.x = expf(v1.x - mx); v1.y = expf(v1.y - mx);
  v1.z = expf(v1.z - mx); v1.w = expf(v1.w - mx);
  float s = v0.x + v0.y + v0.z + v0.w + v1.x + v1.y + v1.z + v1.w;
#pragma unroll
  for (int m = 1; m < 64; m <<= 1) s += __shfl_xor(s, m, 64);
  float r = 1.f / s;
  v0.x *= r; v0.y *= r; v0.z *= r; v0.w *= r;
  v1.x *= r; v1.y *= r; v1.z *= r; v1.w *= r;
  ((float4*)p)[lane*2]     = v0;
  ((float4*)p)[lane*2 + 1] = v1;
}

// ---------------- g2 = leaky((A_x + S_x) @ W1 + b1) -> G2full ----------------
__global__ __launch_bounds__(256) void k_theta(
    const float* __restrict__ H, const float* __restrict__ T1,
    const float* __restrict__ T2, const float* __restrict__ T3,
    const float* __restrict__ SX, const float* __restrict__ coe,
    const float* __restrict__ W1, const float* __restrict__ b1,
    float* __restrict__ G2, int s0){
  __shared__ float GsT[64][68];
  __shared__ float Ws[64][68];
  const int rt = blockIdx.x, cs = blockIdx.y;
  const int tid = threadIdx.x, tx = tid & 15, ty = tid >> 4;
  const float c0 = coe[0]*0.5f, c1 = coe[1], c2 = coe[2], c3 = coe[3];
  const size_t base = (size_t)cs*32768 + (size_t)rt*64*64;
#pragma unroll
  for (int p = 0; p < 16; ++p){
    int q = p*256 + tid;
    int r = q >> 6, d = q & 63;
    size_t idx = base + (size_t)r*64 + d;
    GsT[d][r] = c0*H[idx] + c1*T1[idx] + c2*T2[idx] + c3*T3[idx] + SX[idx];
    Ws[r][d]  = W1[q];
  }
  __syncthreads();
  float acc[4][4] = {};
#pragma unroll 8
  for (int kk = 0; kk < 64; ++kk){
    const float4 a4 = *(const float4*)&GsT[kk][ty*4];
    const float4 b4 = *(const float4*)&Ws[kk][tx*4];
    const float av[4] = {a4.x, a4.y, a4.z, a4.w};
    const float bv[4] = {b4.x, b4.y, b4.z, b4.w};
#pragma unroll
    for (int i = 0; i < 4; ++i)
#pragma unroll
      for (int j = 0; j < 4; ++j) acc[i][j] += av[i]*bv[j];
  }
#pragma unroll
  for (int i = 0; i < 4; ++i){
    int n = rt*64 + ty*4 + i;
#pragma unroll
    for (int j = 0; j < 4; ++j){
      int e = tx*4 + j;
      float v = leaky_(acc[i][j] + b1[e]);
      G2[(size_t)(s0 + cs)*32768 + (size_t)n*64 + e] = v;
    }
  }
}

// ---------------- final: out = leaky(G2 @ Wl + bl), K=32768 split ----------------
__global__ __launch_bounds__(256) void k_final1(
    const float* __restrict__ G2, const float* __restrict__ Wl,
    float* __restrict__ part){
  __shared__ float GsT[32][136];
  __shared__ float Ws[32][136];
  const int pb = blockIdx.x;
  const int tid = threadIdx.x, tx = tid & 15, ty = tid >> 4;
  float acc[8][8] = {};
  for (int k0 = pb*256; k0 < pb*256 + 256; k0 += 32){
    __syncthreads();
#pragma unroll
    for (int p = 0; p < 16; ++p){
      int q = p*256 + tid;
      { int s = q >> 5, c = q & 31;  GsT[c][s] = G2[(size_t)s*32768 + k0 + c]; }
      { int r = q >> 7, o = q & 127; Ws[r][o]  = Wl[(size_t)(k0 + r)*128 + o]; }
    }
    __syncthreads();
#pragma unroll 4
    for (int kk = 0; kk < 32; ++kk){
      float av[8], bv[8];
      *(float4*)&av[0] = *(const float4*)&GsT[kk][ty*8];
      *(float4*)&av[4] = *(const float4*)&GsT[kk][ty*8 + 4];
      *(float4*)&bv[0] = *(const float4*)&Ws[kk][tx*8];
      *(float4*)&bv[4] = *(const float4*)&Ws[kk][tx*8 + 4];
#pragma unroll
      for (int i = 0; i < 8; ++i)
#pragma unroll
        for (int j = 0; j < 8; ++j) acc[i][j] += av[i]*bv[j];
    }
  }
#pragma unroll
  for (int i = 0; i < 8; ++i){
    int s = ty*8 + i;
#pragma unroll
    for (int j = 0; j < 8; ++j){
      int o = tx*8 + j;
      part[(size_t)pb*16384 + (size_t)s*128 + o] = acc[i][j];
    }
  }
}

__global__ __launch_bounds__(256) void k_final2(
    const float* __restrict__ part, const float* __restrict__ bl,
    float* __restrict__ out){
  int idx = blockIdx.x*256 + threadIdx.x;
  int o = idx & 127;
  float acc = bl[o];
  for (int p = 0; p < 128; ++p) acc += part[(size_t)p*16384 + idx];
  out[idx] = leaky_(acc);
}

extern "C" void kernel_launch(void* const* d_in, const int* in_sizes, int n_in,
                              void* d_out, int out_size, void* d_ws, size_t ws_size,
                              hipStream_t stream){
  const float* x    = (const float*)d_in[0];
  const float* adj  = (const float*)d_in[1];
  const float* Wp   = (const float*)d_in[2];
  const float* bp   = (const float*)d_in[3];
  const float* Ksa  = (const float*)d_in[4];
  const float* Vsa  = (const float*)d_in[5];
  const float* bsa  = (const float*)d_in[6];
  const float* temp = (const float*)d_in[7];
  const float* W1   = (const float*)d_in[8];
  const float* b1   = (const float*)d_in[9];
  const float* Wl   = (const float*)d_in[10];
  const float* bl   = (const float*)d_in[11];
  float* out = (float*)d_out;

  float* ws = (float*)d_ws;
  size_t off = 0;
  float* coe  = ws + off; off += 16;
  float* G2   = ws + off; off += (size_t)128*32768;   // 16.8 MB
  float* part = ws + off; off += (size_t)128*16384;   // 8.4 MB
  const size_t fixedOff = off;

  int CH = 128;
  while (CH > 1){
    size_t need = (fixedOff + (size_t)CH*(6*32768 + 2*262144)) * sizeof(float);
    if (need <= ws_size) break;
    CH >>= 1;
  }
  float* H  = ws + off; off += (size_t)CH*32768;
  float* T1 = ws + off; off += (size_t)CH*32768;
  float* T2 = ws + off; off += (size_t)CH*32768;
  float* T3 = ws + off; off += (size_t)CH*32768;
  float* KX = ws + off; off += (size_t)CH*32768;
  float* SX = ws + off; off += (size_t)CH*32768;
  float* P  = ws + off; off += (size_t)CH*262144;
  float* S  = ws + off; off += (size_t)CH*262144;

  k_coe<<<1, 64, 0, stream>>>(temp, coe);

  for (int s0 = 0; s0 < 128; s0 += CH){
    const float* xs = x + (size_t)s0*512;
    k_embed<<<dim3(CH*128), 256, 0, stream>>>(xs, Wp, bp, H);
    // Chebyshev: T1 = adj@H ; T2 = 2*adj@T1 - H ; T3 = 2*adj@T2 - T1
    k_gemm<1,0><<<dim3(8,1,CH), 256, 0, stream>>>(adj, 0, H, 32768, nullptr, 0, T1, 32768);
    k_gemm<1,1><<<dim3(8,1,CH), 256, 0, stream>>>(adj, 0, T1, 32768, H, 32768, T2, 32768);
    k_gemm<1,1><<<dim3(8,1,CH), 256, 0, stream>>>(adj, 0, T2, 32768, T1, 32768, T3, 32768);
    // Kx = Ksa@H
    k_gemm<1,0><<<dim3(8,1,CH), 256, 0, stream>>>(Ksa, 0, H, 32768, nullptr, 0, KX, 32768);
    // P = tanh(H@Kx^T + bsa)
    k_prod<<<dim3(8,8,CH), 256, 0, stream>>>(H, KX, bsa, P);
    // score = Vsa @ P
    k_gemm<8,0><<<dim3(8,8,CH), 256, 0, stream>>>(Vsa, 0, P, 262144, nullptr, 0, S, 262144);
    // SA = softmax(score, axis=-1) in place
    k_softmax<<<dim3(CH*128), 256, 0, stream>>>(S);
    // S_x = SA @ H
    k_gemm<1,0><<<dim3(8,1,CH), 256, 0, stream>>>(S, 262144, H, 32768, nullptr, 0, SX, 32768);
    // g2 = leaky((A_x + S_x)@W1 + b1)
    k_theta<<<dim3(8,CH), 256, 0, stream>>>(H, T1, T2, T3, SX, coe, W1, b1, G2, s0);
  }

  // out = leaky(G2 @ Wl + bl)
  k_final1<<<dim3(128), 256, 0, stream>>>(G2, Wl, part);
  k_final2<<<dim3(64), 256, 0, stream>>>(part, bl, out);
}

// Round 3
// 477.271 us; speedup vs baseline: 3.7704x; 3.7704x over previous
//
#include <hip/hip_runtime.h>
#include <math.h>

#define KORD 3
#ifndef M_PI
#define M_PI 3.14159265358979323846
#endif

typedef __attribute__((ext_vector_type(8))) __bf16 bf16x8;
typedef __attribute__((ext_vector_type(4))) float  f32x4;

__device__ __forceinline__ float leaky_(float v){ return v >= 0.f ? v : 0.01f*v; }

__device__ __forceinline__ f32x4 mfma16(bf16x8 a, bf16x8 b, f32x4 c){
  return __builtin_amdgcn_mfma_f32_16x16x32_bf16(a, b, c, 0, 0, 0);
}

// ---------------- Chebyshev coefficients ----------------
__global__ void k_coe(const float* __restrict__ temp, float* __restrict__ coe){
  if (threadIdx.x == 0 && blockIdx.x == 0){
    for (int i = 0; i <= KORD; ++i){
      float acc = 0.f;
      for (int j = 0; j <= KORD; ++j){
        double th = ((double)(KORD - j) + 0.5) * M_PI / (double)(KORD + 1);
        float t = temp[j]; t = t > 0.f ? t : 0.f;
        acc += t * (float)cos((double)i * th);
      }
      coe[i] = acc * (2.f / (float)(KORD + 1));
    }
  }
}

// ---------------- f32 -> bf16 convert ----------------
__global__ __launch_bounds__(256) void k_cvt(const float* __restrict__ in,
                                             __bf16* __restrict__ out, int n){
  int i = blockIdx.x*256 + threadIdx.x;
  if (i < n) out[i] = (__bf16)in[i];
}

// ---------------- W1t[e][d] = W1[d][e] (bf16) ----------------
__global__ __launch_bounds__(256) void k_w1t(const float* __restrict__ W1,
                                             __bf16* __restrict__ W1t){
  int t = threadIdx.x;
  for (int i = 0; i < 16; ++i){
    int e4 = i*256 + t;
    int e = e4 >> 6, d = e4 & 63;
    W1t[e*64 + d] = (__bf16)W1[d*64 + e];
  }
}

// ---------------- bsaT[m][n] = bsa[n][m] (f32) ----------------
__global__ __launch_bounds__(256) void k_bsat(const float* __restrict__ bsa,
                                              float* __restrict__ bsaT){
  __shared__ float Ls[64][65];
  int n0 = blockIdx.x*64, m0 = blockIdx.y*64;
  int t = threadIdx.x;
  for (int i = 0; i < 16; ++i){
    int e = i*256 + t; int r = e >> 6, c = e & 63;
    Ls[r][c] = bsa[(size_t)(n0 + r)*512 + m0 + c];
  }
  __syncthreads();
  for (int i = 0; i < 16; ++i){
    int e = i*256 + t; int r = e >> 6, c = e & 63;
    bsaT[(size_t)(m0 + r)*512 + n0 + c] = Ls[c][r];
  }
}

// ---------------- embed: Ht[j][n] = bf16(x[cs,n]*Wp[d]+bp[d]), j=cs*64+d ----------------
__global__ __launch_bounds__(256) void k_embed(const float* __restrict__ x,
    const float* __restrict__ Wp, const float* __restrict__ bp,
    __bf16* __restrict__ Ht){
  int idx = blockIdx.x*256 + threadIdx.x;
  int n = idx & 511, j = idx >> 9;
  int cs = j >> 6, d = j & 63;
  Ht[idx] = (__bf16)(x[cs*512 + n]*Wp[d] + bp[d]);
}

// ---------------- transpose j-major -> nd: out[cs][n][d] = in[cs*64+d][n] ----------------
__global__ __launch_bounds__(256) void k_tr(const __bf16* __restrict__ in,
                                            __bf16* __restrict__ out){
  __shared__ float Ls[64][65];
  int cs = blockIdx.x, n0 = blockIdx.y*64;
  int t = threadIdx.x;
  for (int i = 0; i < 16; ++i){
    int e = i*256 + t; int d = e >> 6, nn = e & 63;
    Ls[d][nn] = (float)in[(size_t)(cs*64 + d)*512 + n0 + nn];
  }
  __syncthreads();
  for (int i = 0; i < 16; ++i){
    int e = i*256 + t; int nn = e >> 6, d = e & 63;
    out[((size_t)cs*512 + n0 + nn)*64 + d] = (__bf16)Ls[d][nn];
  }
}

// ---------------- combo: Gnd[cs][n][d] = c0/2*H + c1*T1 + c2*T2 + c3*T3 + SX (transposed) ----------------
__global__ __launch_bounds__(256) void k_combo(const __bf16* __restrict__ Ht,
    const __bf16* __restrict__ T1t, const __bf16* __restrict__ T2t,
    const __bf16* __restrict__ T3t, const __bf16* __restrict__ SXt,
    const float* __restrict__ coe, __bf16* __restrict__ Gnd){
  __shared__ float Ls[64][65];
  int cs = blockIdx.x, n0 = blockIdx.y*64;
  int t = threadIdx.x;
  float c0 = coe[0]*0.5f, c1 = coe[1], c2 = coe[2], c3 = coe[3];
  for (int i = 0; i < 16; ++i){
    int e = i*256 + t; int d = e >> 6, nn = e & 63;
    size_t idx = (size_t)(cs*64 + d)*512 + n0 + nn;
    Ls[d][nn] = c0*(float)Ht[idx] + c1*(float)T1t[idx] + c2*(float)T2t[idx]
              + c3*(float)T3t[idx] + (float)SXt[idx];
  }
  __syncthreads();
  for (int i = 0; i < 16; ++i){
    int e = i*256 + t; int nn = e >> 6, d = e & 63;
    Gnd[((size_t)cs*512 + n0 + nn)*64 + d] = (__bf16)Ls[d][nn];
  }
}

// ---------------- MFMA GEMM: C[z] = A[z] * B[z]^T (+epilogue), K-contig operands ----------------
// EPI: 0 = bf16 out; 1 = bf16 out 2*acc - Z; 2 = bf16 out tanh(acc + Ef[row*512+col]);
//      3 = f32 out;  4 = f32 out leaky(acc + Ef[col])
template<int BM, int BN, int WM, int WN, int EPI>
__global__ __launch_bounds__(256) void gbt(
    const __bf16* __restrict__ A, size_t aB, int lda,
    const __bf16* __restrict__ B, size_t bB, int ldb,
    const void*  __restrict__ E, size_t eB,
    void* __restrict__ C, size_t cB, int ldc, int K){
  constexpr int WTM = BM/WM, WTN = BN/WN;
  constexpr int FM = WTM/16, FN = WTN/16;
  constexpr int LDK = 72;
  __shared__ __bf16 As[BM*LDK];
  __shared__ __bf16 Bs[BN*LDK];
  const int tid = threadIdx.x;
  const int wave = tid >> 6, lane = tid & 63;
  const int wm = wave % WM, wn = wave / WM;
  const int m0 = blockIdx.x*BM, n0 = blockIdx.y*BN;
  const int z = blockIdx.z;
  const __bf16* Ab = A + (size_t)z*aB + (size_t)m0*lda;
  const __bf16* Bb = B + (size_t)z*bB + (size_t)n0*ldb;
  f32x4 acc[FM][FN] = {};
  for (int k0 = 0; k0 < K; k0 += 64){
    __syncthreads();
    constexpr int AIT = BM*64/(256*8);
#pragma unroll
    for (int i = 0; i < AIT; ++i){
      int e = i*256 + tid; int r = e >> 3, c = (e & 7)*8;
      *(float4*)&As[r*LDK + c] = *(const float4*)&Ab[(size_t)r*lda + k0 + c];
    }
    constexpr int BIT = BN*64/(256*8);
#pragma unroll
    for (int i = 0; i < BIT; ++i){
      int e = i*256 + tid; int r = e >> 3, c = (e & 7)*8;
      *(float4*)&Bs[r*LDK + c] = *(const float4*)&Bb[(size_t)r*ldb + k0 + c];
    }
    __syncthreads();
#pragma unroll
    for (int ks = 0; ks < 2; ++ks){
      bf16x8 af[FM], bfr[FN];
      const int ko = ks*32 + (lane >> 4)*8;
#pragma unroll
      for (int i = 0; i < FM; ++i)
        af[i] = *(const bf16x8*)&As[(wm*WTM + i*16 + (lane & 15))*LDK + ko];
#pragma unroll
      for (int j = 0; j < FN; ++j)
        bfr[j] = *(const bf16x8*)&Bs[(wn*WTN + j*16 + (lane & 15))*LDK + ko];
#pragma unroll
      for (int i = 0; i < FM; ++i)
#pragma unroll
        for (int j = 0; j < FN; ++j)
          acc[i][j] = mfma16(af[i], bfr[j], acc[i][j]);
    }
  }
  __bf16* Cb = (__bf16*)C + (size_t)z*cB;
  float*  Cf = (float*)C  + (size_t)z*cB;
  const __bf16* Zb = (const __bf16*)E + (size_t)z*eB;
  const float*  Ef = (const float*)E;
  const int lr = (lane >> 4)*4, lc = lane & 15;
#pragma unroll
  for (int i = 0; i < FM; ++i){
    int row = m0 + wm*WTM + i*16 + lr;
#pragma unroll
    for (int j = 0; j < FN; ++j){
      int col = n0 + wn*WTN + j*16 + lc;
#pragma unroll
      for (int r = 0; r < 4; ++r){
        float v = acc[i][j][r];
        size_t idx = (size_t)(row + r)*ldc + col;
        if (EPI == 0){ Cb[idx] = (__bf16)v; }
        else if (EPI == 1){ Cb[idx] = (__bf16)(2.f*v - (float)Zb[idx]); }
        else if (EPI == 2){ Cb[idx] = (__bf16)tanhf(v + Ef[(size_t)(row + r)*512 + col]); }
        else if (EPI == 3){ Cf[idx] = v; }
        else { float tt = v + Ef[col]; Cf[idx] = tt >= 0.f ? tt : 0.01f*tt; }
      }
    }
  }
}

// ---------------- softmax rows of 512 (f32 in, bf16 out) ----------------
__global__ __launch_bounds__(256) void k_softmax(const float* __restrict__ S,
                                                 __bf16* __restrict__ SA){
  int row  = blockIdx.x*4 + (threadIdx.x >> 6);
  int lane = threadIdx.x & 63;
  const float4* p = (const float4*)(S + (size_t)row*512);
  float4 v0 = p[lane*2];
  float4 v1 = p[lane*2 + 1];
  float mx = fmaxf(fmaxf(fmaxf(v0.x, v0.y), fmaxf(v0.z, v0.w)),
                   fmaxf(fmaxf(v1.x, v1.y), fmaxf(v1.z, v1.w)));
#pragma unroll
  for (int m = 1; m < 64; m <<= 1) mx = fmaxf(mx, __shfl_xor(mx, m, 64));
  v0.x = expf(v0.x - mx); v0.y = expf(v0.y - mx);
  v0.z = expf(v0.z - mx); v0.w = expf(v0.w - mx);
  v1.x = expf(v1.x - mx); v1.y = expf(v1.y - mx);
  v1.z = expf(v1.z - mx); v1.w = expf(v1.w - mx);
  float s = v0.x + v0.y + v0.z + v0.w + v1.x + v1.y + v1.z + v1.w;
#pragma unroll
  for (int m = 1; m < 64; m <<= 1) s += __shfl_xor(s, m, 64);
  float r = 1.f / s;
  bf16x8 o;
  o[0] = (__bf16)(v0.x*r); o[1] = (__bf16)(v0.y*r);
  o[2] = (__bf16)(v0.z*r); o[3] = (__bf16)(v0.w*r);
  o[4] = (__bf16)(v1.x*r); o[5] = (__bf16)(v1.y*r);
  o[6] = (__bf16)(v1.z*r); o[7] = (__bf16)(v1.w*r);
  ((bf16x8*)(SA + (size_t)row*512))[lane] = o;
}

// ---------------- final: out = leaky(G2 @ Wl + bl), f32, K=32768 split ----------------
__global__ __launch_bounds__(256) void k_final1(
    const float* __restrict__ G2, const float* __restrict__ Wl,
    float* __restrict__ part){
  __shared__ float GsT[32][136];
  __shared__ float Ws[32][136];
  const int pb = blockIdx.x;
  const int tid = threadIdx.x, tx = tid & 15, ty = tid >> 4;
  float acc[8][8] = {};
  for (int k0 = pb*256; k0 < pb*256 + 256; k0 += 32){
    __syncthreads();
#pragma unroll
    for (int p = 0; p < 16; ++p){
      int q = p*256 + tid;
      { int s = q >> 5, c = q & 31;  GsT[c][s] = G2[(size_t)s*32768 + k0 + c]; }
      { int r = q >> 7, o = q & 127; Ws[r][o]  = Wl[(size_t)(k0 + r)*128 + o]; }
    }
    __syncthreads();
#pragma unroll 4
    for (int kk = 0; kk < 32; ++kk){
      float av[8], bv[8];
      *(float4*)&av[0] = *(const float4*)&GsT[kk][ty*8];
      *(float4*)&av[4] = *(const float4*)&GsT[kk][ty*8 + 4];
      *(float4*)&bv[0] = *(const float4*)&Ws[kk][tx*8];
      *(float4*)&bv[4] = *(const float4*)&Ws[kk][tx*8 + 4];
#pragma unroll
      for (int i = 0; i < 8; ++i)
#pragma unroll
        for (int j = 0; j < 8; ++j) acc[i][j] += av[i]*bv[j];
    }
  }
#pragma unroll
  for (int i = 0; i < 8; ++i){
    int s = ty*8 + i;
#pragma unroll
    for (int j = 0; j < 8; ++j){
      int o = tx*8 + j;
      part[(size_t)pb*16384 + (size_t)s*128 + o] = acc[i][j];
    }
  }
}

__global__ __launch_bounds__(256) void k_final2(
    const float* __restrict__ part, const float* __restrict__ bl,
    float* __restrict__ out){
  int idx = blockIdx.x*256 + threadIdx.x;
  int o = idx & 127;
  float acc = bl[o];
  for (int p = 0; p < 128; ++p) acc += part[(size_t)p*16384 + idx];
  out[idx] = leaky_(acc);
}

extern "C" void kernel_launch(void* const* d_in, const int* in_sizes, int n_in,
                              void* d_out, int out_size, void* d_ws, size_t ws_size,
                              hipStream_t stream){
  const float* x    = (const float*)d_in[0];
  const float* adj  = (const float*)d_in[1];
  const float* Wp   = (const float*)d_in[2];
  const float* bp   = (const float*)d_in[3];
  const float* Ksa  = (const float*)d_in[4];
  const float* Vsa  = (const float*)d_in[5];
  const float* bsa  = (const float*)d_in[6];
  const float* temp = (const float*)d_in[7];
  const float* W1   = (const float*)d_in[8];
  const float* b1   = (const float*)d_in[9];
  const float* Wl   = (const float*)d_in[10];
  const float* bl   = (const float*)d_in[11];
  float* out = (float*)d_out;

  // ---- workspace carve-up (bytes), chunk-adaptive to fit ws_size ----
  char* ws = (char*)d_ws;
  size_t off = 0;
  auto alloc = [&](size_t bytes){ void* p = ws + off; off += (bytes + 255) & ~(size_t)255; return p; };
  float* coe   = (float*)alloc(64);
  float* G2    = (float*)alloc((size_t)128*32768*4);    // 16.8 MB
  float* part  = (float*)alloc((size_t)128*16384*4);    // 8.4 MB
  float* bsaT  = (float*)alloc((size_t)512*512*4);      // 1 MB
  __bf16* adjb = (__bf16*)alloc((size_t)512*512*2);
  __bf16* Ksab = (__bf16*)alloc((size_t)512*512*2);
  __bf16* Vsab = (__bf16*)alloc((size_t)512*512*2);
  __bf16* W1t  = (__bf16*)alloc((size_t)64*64*2);
  const size_t fixedOff = off;

  // per-chunk need: 9 bf16 [CH*64][512] bufs + Pt bf16 [CH][512][512] + S f32 [CH][512][512]
  int CH = 128;
  while (CH > 2){
    size_t need = fixedOff + (size_t)CH*(9*65536 + 524288 + 1048576) + 65536;
    if (need <= ws_size) break;
    CH >>= 1;
  }
  __bf16* Ht   = (__bf16*)alloc((size_t)CH*65536);
  __bf16* T1t  = (__bf16*)alloc((size_t)CH*65536);
  __bf16* T2t  = (__bf16*)alloc((size_t)CH*65536);
  __bf16* T3t  = (__bf16*)alloc((size_t)CH*65536);
  __bf16* KXt  = (__bf16*)alloc((size_t)CH*65536);
  __bf16* KXnd = (__bf16*)alloc((size_t)CH*65536);
  __bf16* Hnd  = (__bf16*)alloc((size_t)CH*65536);
  __bf16* SXt  = (__bf16*)alloc((size_t)CH*65536);
  __bf16* Gnd  = (__bf16*)alloc((size_t)CH*65536);
  __bf16* Pt   = (__bf16*)alloc((size_t)CH*524288);
  float*  S    = (float*)alloc((size_t)CH*1048576);
  __bf16* SAb  = Pt;  // alias: Pt dead after score GEMM

  k_coe<<<1, 64, 0, stream>>>(temp, coe);
  k_cvt<<<1024, 256, 0, stream>>>(adj, adjb, 512*512);
  k_cvt<<<1024, 256, 0, stream>>>(Ksa, Ksab, 512*512);
  k_cvt<<<1024, 256, 0, stream>>>(Vsa, Vsab, 512*512);
  k_w1t<<<1, 256, 0, stream>>>(W1, W1t);
  k_bsat<<<dim3(8,8), 256, 0, stream>>>(bsa, bsaT);

  for (int s0 = 0; s0 < 128; s0 += CH){
    // Ht[j][n] embed for this chunk
    k_embed<<<dim3(CH*128), 256, 0, stream>>>(x + (size_t)s0*512, Wp, bp, Ht);
    // Hnd[cs][n][d]
    k_tr<<<dim3(CH,8), 256, 0, stream>>>(Ht, Hnd);
    // Chebyshev (j-major): T1t = Ht*adj^T ; T2t = 2*T1t*adj^T - Ht ; T3t = 2*T2t*adj^T - T1t
    gbt<128,128,2,2,0><<<dim3(CH/2,4,1), 256, 0, stream>>>(Ht, 0, 512, adjb, 0, 512, nullptr, 0, T1t, 0, 512, 512);
    gbt<128,128,2,2,1><<<dim3(CH/2,4,1), 256, 0, stream>>>(T1t, 0, 512, adjb, 0, 512, Ht, 0, T2t, 0, 512, 512);
    gbt<128,128,2,2,1><<<dim3(CH/2,4,1), 256, 0, stream>>>(T2t, 0, 512, adjb, 0, 512, T1t, 0, T3t, 0, 512, 512);
    // KXt = Ht*Ksa^T ; transpose to KXnd
    gbt<128,128,2,2,0><<<dim3(CH/2,4,1), 256, 0, stream>>>(Ht, 0, 512, Ksab, 0, 512, nullptr, 0, KXt, 0, 512, 512);
    k_tr<<<dim3(CH,8), 256, 0, stream>>>(KXt, KXnd);
    // Pt[cs][m][n] = tanh(KXnd[cs]*Hnd[cs]^T + bsaT)  (K=64)
    gbt<128,128,2,2,2><<<dim3(4,4,CH), 256, 0, stream>>>(KXnd, 32768, 64, Hnd, 32768, 64,
                                                         bsaT, 0, Pt, 262144, 512, 64);
    // S[cs] = Vsa * Pt[cs]^T  (f32 out)
    gbt<128,128,2,2,3><<<dim3(4,4,CH), 256, 0, stream>>>(Vsab, 0, 512, Pt, 262144, 512,
                                                         nullptr, 0, S, 262144, 512, 512);
    // SA = softmax rows -> bf16 (into Pt buffer)
    k_softmax<<<dim3(CH*128), 256, 0, stream>>>(S, SAb);
    // SXt[cs*64+d][n] = Ht_slice * SA[cs]^T
    gbt<64,128,2,2,0><<<dim3(1,4,CH), 256, 0, stream>>>(Ht, 32768, 512, SAb, 262144, 512,
                                                        nullptr, 0, SXt, 32768, 512, 512);
    // Gnd = transpose(c0/2*Ht + c1*T1t + c2*T2t + c3*T3t + SXt)
    k_combo<<<dim3(CH,8), 256, 0, stream>>>(Ht, T1t, T2t, T3t, SXt, coe, Gnd);
    // G2[s0+cs][n][e] = leaky(Gnd[cs]*W1t^T + b1)  (K=64, f32 out)
    gbt<128,64,2,2,4><<<dim3(4,1,CH), 256, 0, stream>>>(Gnd, 32768, 64, W1t, 0, 64,
                                                        b1, 0, G2 + (size_t)s0*32768, 32768, 64, 64);
  }

  // out = leaky(G2 @ Wl + bl)
  k_final1<<<dim3(128), 256, 0, stream>>>(G2, Wl, part);
  k_final2<<<dim3(64), 256, 0, stream>>>(part, bl, out);
}

// Round 4
// 394.571 us; speedup vs baseline: 4.5606x; 1.2096x over previous
//
#include <hip/hip_runtime.h>
#include <math.h>

#define KORD 3
#ifndef M_PI
#define M_PI 3.14159265358979323846
#endif

typedef __attribute__((ext_vector_type(8))) __bf16 bf16x8;
typedef __attribute__((ext_vector_type(4))) float  f32x4;

__device__ __forceinline__ float leaky_(float v){ return v >= 0.f ? v : 0.01f*v; }

__device__ __forceinline__ f32x4 mfma16(bf16x8 a, bf16x8 b, f32x4 c){
  return __builtin_amdgcn_mfma_f32_16x16x32_bf16(a, b, c, 0, 0, 0);
}

// ---------------- Chebyshev coefficients ----------------
__global__ void k_coe(const float* __restrict__ temp, float* __restrict__ coe){
  if (threadIdx.x == 0 && blockIdx.x == 0){
    for (int i = 0; i <= KORD; ++i){
      float acc = 0.f;
      for (int j = 0; j <= KORD; ++j){
        double th = ((double)(KORD - j) + 0.5) * M_PI / (double)(KORD + 1);
        float t = temp[j]; t = t > 0.f ? t : 0.f;
        acc += t * (float)cos((double)i * th);
      }
      coe[i] = acc * (2.f / (float)(KORD + 1));
    }
  }
}

// ---------------- f32 -> bf16 convert ----------------
__global__ __launch_bounds__(256) void k_cvt(const float* __restrict__ in,
                                             __bf16* __restrict__ out, int n){
  int i = blockIdx.x*256 + threadIdx.x;
  if (i < n) out[i] = (__bf16)in[i];
}

// ---------------- W1t[e][d] = W1[d][e] (bf16) ----------------
__global__ __launch_bounds__(256) void k_w1t(const float* __restrict__ W1,
                                             __bf16* __restrict__ W1t){
  int t = threadIdx.x;
  for (int i = 0; i < 16; ++i){
    int e4 = i*256 + t;
    int e = e4 >> 6, d = e4 & 63;
    W1t[e*64 + d] = (__bf16)W1[d*64 + e];
  }
}

// ---------------- Wlt[o][k] = Wl[k][o] (bf16), Wl: [32768][128] ----------------
__global__ __launch_bounds__(256) void k_wlt(const float* __restrict__ Wl,
                                             __bf16* __restrict__ Wlt){
  __shared__ float Ls[64][65];
  int k0 = blockIdx.x*64, o0 = blockIdx.y*64;
  int t = threadIdx.x;
  for (int i = 0; i < 16; ++i){
    int e = i*256 + t; int r = e >> 6, c = e & 63;
    Ls[r][c] = Wl[(size_t)(k0 + r)*128 + o0 + c];
  }
  __syncthreads();
  for (int i = 0; i < 16; ++i){
    int e = i*256 + t; int r = e >> 6, c = e & 63;
    Wlt[(size_t)(o0 + r)*32768 + k0 + c] = (__bf16)Ls[c][r];
  }
}

// ---------------- bsaT[m][n] = bsa[n][m] (f32) ----------------
__global__ __launch_bounds__(256) void k_bsat(const float* __restrict__ bsa,
                                              float* __restrict__ bsaT){
  __shared__ float Ls[64][65];
  int n0 = blockIdx.x*64, m0 = blockIdx.y*64;
  int t = threadIdx.x;
  for (int i = 0; i < 16; ++i){
    int e = i*256 + t; int r = e >> 6, c = e & 63;
    Ls[r][c] = bsa[(size_t)(n0 + r)*512 + m0 + c];
  }
  __syncthreads();
  for (int i = 0; i < 16; ++i){
    int e = i*256 + t; int r = e >> 6, c = e & 63;
    bsaT[(size_t)(m0 + r)*512 + n0 + c] = Ls[c][r];
  }
}

// ---------------- embed both layouts: Ht[j][n] and Hnd[cs][n][d] ----------------
__global__ __launch_bounds__(256) void k_embed2(const float* __restrict__ x,
    const float* __restrict__ Wp, const float* __restrict__ bp,
    __bf16* __restrict__ Ht, __bf16* __restrict__ Hnd){
  __shared__ float Ls[64][65];
  int cs = blockIdx.x, n0 = blockIdx.y*64;
  int t = threadIdx.x;
  for (int i = 0; i < 16; ++i){
    int e = i*256 + t; int d = e >> 6, nn = e & 63;
    float v = x[cs*512 + n0 + nn]*Wp[d] + bp[d];
    Ls[d][nn] = v;
    Ht[(size_t)(cs*64 + d)*512 + n0 + nn] = (__bf16)v;
  }
  __syncthreads();
  for (int i = 0; i < 16; ++i){
    int e = i*256 + t; int nn = e >> 6, d = e & 63;
    Hnd[((size_t)cs*512 + n0 + nn)*64 + d] = (__bf16)Ls[d][nn];
  }
}

// ---------------- combo: Gnd[cs][n][d] = c0/2*H + c1*T1 + c2*T2 + c3*T3 + SX (transposed) ----------------
__global__ __launch_bounds__(256) void k_combo(const __bf16* __restrict__ Ht,
    const __bf16* __restrict__ T1t, const __bf16* __restrict__ T2t,
    const __bf16* __restrict__ T3t, const __bf16* __restrict__ SXt,
    const float* __restrict__ coe, __bf16* __restrict__ Gnd){
  __shared__ float Ls[64][65];
  int cs = blockIdx.x, n0 = blockIdx.y*64;
  int t = threadIdx.x;
  float c0 = coe[0]*0.5f, c1 = coe[1], c2 = coe[2], c3 = coe[3];
  for (int i = 0; i < 16; ++i){
    int e = i*256 + t; int d = e >> 6, nn = e & 63;
    size_t idx = (size_t)(cs*64 + d)*512 + n0 + nn;
    Ls[d][nn] = c0*(float)Ht[idx] + c1*(float)T1t[idx] + c2*(float)T2t[idx]
              + c3*(float)T3t[idx] + (float)SXt[idx];
  }
  __syncthreads();
  for (int i = 0; i < 16; ++i){
    int e = i*256 + t; int nn = e >> 6, d = e & 63;
    Gnd[((size_t)cs*512 + n0 + nn)*64 + d] = (__bf16)Ls[d][nn];
  }
}

// ---------------- MFMA GEMM: C[z] = A[z] * B[z]^T (+epilogue), K-contig operands ----------------
// EPI: 0 = bf16 out; 1 = bf16 out 2*acc - Z; 2 = bf16 out tanh(acc + Ef[row*512+col]);
//      3 = f32 out;  5 = bf16 out leaky(acc + Ef[col])
template<int BM, int BN, int WM, int WN, int EPI>
__global__ __launch_bounds__(256) void gbt(
    const __bf16* __restrict__ A, size_t aB, int lda,
    const __bf16* __restrict__ B, size_t bB, int ldb,
    const void*  __restrict__ E, size_t eB,
    void* __restrict__ C, size_t cB, int ldc, int K){
  constexpr int WTM = BM/WM, WTN = BN/WN;
  constexpr int FM = WTM/16, FN = WTN/16;
  constexpr int LDK = 72;
  __shared__ __bf16 As[BM*LDK];
  __shared__ __bf16 Bs[BN*LDK];
  const int tid = threadIdx.x;
  const int wave = tid >> 6, lane = tid & 63;
  const int wm = wave % WM, wn = wave / WM;
  const int m0 = blockIdx.x*BM, n0 = blockIdx.y*BN;
  const int z = blockIdx.z;
  const __bf16* Ab = A + (size_t)z*aB + (size_t)m0*lda;
  const __bf16* Bb = B + (size_t)z*bB + (size_t)n0*ldb;
  f32x4 acc[FM][FN] = {};
  for (int k0 = 0; k0 < K; k0 += 64){
    __syncthreads();
    constexpr int AIT = BM*64/(256*8);
#pragma unroll
    for (int i = 0; i < AIT; ++i){
      int e = i*256 + tid; int r = e >> 3, c = (e & 7)*8;
      *(float4*)&As[r*LDK + c] = *(const float4*)&Ab[(size_t)r*lda + k0 + c];
    }
    constexpr int BIT = BN*64/(256*8);
#pragma unroll
    for (int i = 0; i < BIT; ++i){
      int e = i*256 + tid; int r = e >> 3, c = (e & 7)*8;
      *(float4*)&Bs[r*LDK + c] = *(const float4*)&Bb[(size_t)r*ldb + k0 + c];
    }
    __syncthreads();
#pragma unroll
    for (int ks = 0; ks < 2; ++ks){
      bf16x8 af[FM], bfr[FN];
      const int ko = ks*32 + (lane >> 4)*8;
#pragma unroll
      for (int i = 0; i < FM; ++i)
        af[i] = *(const bf16x8*)&As[(wm*WTM + i*16 + (lane & 15))*LDK + ko];
#pragma unroll
      for (int j = 0; j < FN; ++j)
        bfr[j] = *(const bf16x8*)&Bs[(wn*WTN + j*16 + (lane & 15))*LDK + ko];
#pragma unroll
      for (int i = 0; i < FM; ++i)
#pragma unroll
        for (int j = 0; j < FN; ++j)
          acc[i][j] = mfma16(af[i], bfr[j], acc[i][j]);
    }
  }
  __bf16* Cb = (__bf16*)C + (size_t)z*cB;
  float*  Cf = (float*)C  + (size_t)z*cB;
  const __bf16* Zb = (const __bf16*)E + (size_t)z*eB;
  const float*  Ef = (const float*)E;
  const int lr = (lane >> 4)*4, lc = lane & 15;
#pragma unroll
  for (int i = 0; i < FM; ++i){
    int row = m0 + wm*WTM + i*16 + lr;
#pragma unroll
    for (int j = 0; j < FN; ++j){
      int col = n0 + wn*WTN + j*16 + lc;
#pragma unroll
      for (int r = 0; r < 4; ++r){
        float v = acc[i][j][r];
        size_t idx = (size_t)(row + r)*ldc + col;
        if (EPI == 0){ Cb[idx] = (__bf16)v; }
        else if (EPI == 1){ Cb[idx] = (__bf16)(2.f*v - (float)Zb[idx]); }
        else if (EPI == 2){ Cb[idx] = (__bf16)tanhf(v + Ef[(size_t)(row + r)*512 + col]); }
        else if (EPI == 3){ Cf[idx] = v; }
        else if (EPI == 5){ float tt = v + Ef[col]; Cb[idx] = (__bf16)(tt >= 0.f ? tt : 0.01f*tt); }
      }
    }
  }
}

// ---------------- softmax rows of 512 (f32 in, bf16 out) ----------------
__global__ __launch_bounds__(256) void k_softmax(const float* __restrict__ S,
                                                 __bf16* __restrict__ SA){
  int row  = blockIdx.x*4 + (threadIdx.x >> 6);
  int lane = threadIdx.x & 63;
  const float4* p = (const float4*)(S + (size_t)row*512);
  float4 v0 = p[lane*2];
  float4 v1 = p[lane*2 + 1];
  float mx = fmaxf(fmaxf(fmaxf(v0.x, v0.y), fmaxf(v0.z, v0.w)),
                   fmaxf(fmaxf(v1.x, v1.y), fmaxf(v1.z, v1.w)));
#pragma unroll
  for (int m = 1; m < 64; m <<= 1) mx = fmaxf(mx, __shfl_xor(mx, m, 64));
  v0.x = expf(v0.x - mx); v0.y = expf(v0.y - mx);
  v0.z = expf(v0.z - mx); v0.w = expf(v0.w - mx);
  v1.x = expf(v1.x - mx); v1.y = expf(v1.y - mx);
  v1.z = expf(v1.z - mx); v1.w = expf(v1.w - mx);
  float s = v0.x + v0.y + v0.z + v0.w + v1.x + v1.y + v1.z + v1.w;
#pragma unroll
  for (int m = 1; m < 64; m <<= 1) s += __shfl_xor(s, m, 64);
  float r = 1.f / s;
  bf16x8 o;
  o[0] = (__bf16)(v0.x*r); o[1] = (__bf16)(v0.y*r);
  o[2] = (__bf16)(v0.z*r); o[3] = (__bf16)(v0.w*r);
  o[4] = (__bf16)(v1.x*r); o[5] = (__bf16)(v1.y*r);
  o[6] = (__bf16)(v1.z*r); o[7] = (__bf16)(v1.w*r);
  ((bf16x8*)(SA + (size_t)row*512))[lane] = o;
}

// ---------------- reduce 32 K-partials + bias + leaky ----------------
__global__ __launch_bounds__(256) void k_final2(
    const float* __restrict__ part, const float* __restrict__ bl,
    float* __restrict__ out){
  int idx = blockIdx.x*256 + threadIdx.x;
  int o = idx & 127;
  float acc = bl[o];
#pragma unroll
  for (int p = 0; p < 32; ++p) acc += part[(size_t)p*16384 + idx];
  out[idx] = leaky_(acc);
}

extern "C" void kernel_launch(void* const* d_in, const int* in_sizes, int n_in,
                              void* d_out, int out_size, void* d_ws, size_t ws_size,
                              hipStream_t stream){
  const float* x    = (const float*)d_in[0];
  const float* adj  = (const float*)d_in[1];
  const float* Wp   = (const float*)d_in[2];
  const float* bp   = (const float*)d_in[3];
  const float* Ksa  = (const float*)d_in[4];
  const float* Vsa  = (const float*)d_in[5];
  const float* bsa  = (const float*)d_in[6];
  const float* temp = (const float*)d_in[7];
  const float* W1   = (const float*)d_in[8];
  const float* b1   = (const float*)d_in[9];
  const float* Wl   = (const float*)d_in[10];
  const float* bl   = (const float*)d_in[11];
  float* out = (float*)d_out;

  // ---- workspace carve-up (bytes), chunk-adaptive ----
  char* ws = (char*)d_ws;
  size_t off = 0;
  auto alloc = [&](size_t bytes){ void* p = ws + off; off += (bytes + 255) & ~(size_t)255; return p; };
  float*  coe  = (float*)alloc(64);
  __bf16* G2b  = (__bf16*)alloc((size_t)128*32768*2);   // 8.4 MB, [B*L][N*D] bf16
  __bf16* Wlt  = (__bf16*)alloc((size_t)128*32768*2);   // 8.4 MB, [DM][N*D] bf16
  float*  part = (float*)alloc((size_t)32*16384*4);     // 2.1 MB
  float*  bsaT = (float*)alloc((size_t)512*512*4);      // 1 MB
  __bf16* adjb = (__bf16*)alloc((size_t)512*512*2);
  __bf16* Ksab = (__bf16*)alloc((size_t)512*512*2);
  __bf16* Vsab = (__bf16*)alloc((size_t)512*512*2);
  __bf16* W1t  = (__bf16*)alloc((size_t)64*64*2);
  const size_t fixedOff = off;

  // per-slice: 8 bf16 [64*512] bufs + Pt bf16 [512][512] + S f32 [512][512]
  int CH = 128;
  while (CH > 2){
    size_t need = fixedOff + (size_t)CH*(8*65536 + 524288 + 1048576) + 65536;
    if (need <= ws_size) break;
    CH >>= 1;
  }
  __bf16* Ht   = (__bf16*)alloc((size_t)CH*65536);
  __bf16* T1t  = (__bf16*)alloc((size_t)CH*65536);
  __bf16* T2t  = (__bf16*)alloc((size_t)CH*65536);
  __bf16* T3t  = (__bf16*)alloc((size_t)CH*65536);
  __bf16* KXnd = (__bf16*)alloc((size_t)CH*65536);
  __bf16* Hnd  = (__bf16*)alloc((size_t)CH*65536);
  __bf16* SXt  = (__bf16*)alloc((size_t)CH*65536);
  __bf16* Gnd  = (__bf16*)alloc((size_t)CH*65536);
  __bf16* Pt   = (__bf16*)alloc((size_t)CH*524288);
  float*  S    = (float*)alloc((size_t)CH*1048576);
  __bf16* SAb  = Pt;  // alias: Pt dead after score GEMM

  // preprocessing
  k_coe<<<1, 64, 0, stream>>>(temp, coe);
  k_cvt<<<1024, 256, 0, stream>>>(adj, adjb, 512*512);
  k_cvt<<<1024, 256, 0, stream>>>(Ksa, Ksab, 512*512);
  k_cvt<<<1024, 256, 0, stream>>>(Vsa, Vsab, 512*512);
  k_w1t<<<1, 256, 0, stream>>>(W1, W1t);
  k_wlt<<<dim3(512,2), 256, 0, stream>>>(Wl, Wlt);
  k_bsat<<<dim3(8,8), 256, 0, stream>>>(bsa, bsaT);

  for (int s0 = 0; s0 < 128; s0 += CH){
    // embed both layouts
    k_embed2<<<dim3(CH,8), 256, 0, stream>>>(x + (size_t)s0*512, Wp, bp, Ht, Hnd);
    // Chebyshev (j-major): T1t = Ht*adj^T ; T2t = 2*T1t*adj^T - Ht ; T3t = 2*T2t*adj^T - T1t
    gbt<128,128,2,2,0><<<dim3(CH/2,4,1), 256, 0, stream>>>(Ht, 0, 512, adjb, 0, 512, nullptr, 0, T1t, 0, 512, 512);
    gbt<128,128,2,2,1><<<dim3(CH/2,4,1), 256, 0, stream>>>(T1t, 0, 512, adjb, 0, 512, Ht, 0, T2t, 0, 512, 512);
    gbt<128,128,2,2,1><<<dim3(CH/2,4,1), 256, 0, stream>>>(T2t, 0, 512, adjb, 0, 512, T1t, 0, T3t, 0, 512, 512);
    // KXnd[cs][m][d] = Ksa @ H  (direct nd layout: C[m][d] = sum_n Ksa[m][n]*Ht[d][n])
    gbt<128,64,2,2,0><<<dim3(4,1,CH), 256, 0, stream>>>(Ksab, 0, 512, Ht, 65536/2, 512,
                                                        nullptr, 0, KXnd, 32768, 64, 512);
    // Pt[cs][m][n] = tanh(KXnd[cs]*Hnd[cs]^T + bsaT)  (K=64)
    gbt<128,128,2,2,2><<<dim3(4,4,CH), 256, 0, stream>>>(KXnd, 32768, 64, Hnd, 32768, 64,
                                                         bsaT, 0, Pt, 262144, 512, 64);
    // S[cs] = Vsa * Pt[cs]^T  (f32 out)
    gbt<128,128,2,2,3><<<dim3(4,4,CH), 256, 0, stream>>>(Vsab, 0, 512, Pt, 262144, 512,
                                                         nullptr, 0, S, 262144, 512, 512);
    // SA = softmax rows -> bf16 (into Pt buffer)
    k_softmax<<<dim3(CH*128), 256, 0, stream>>>(S, SAb);
    // SXt[cs*64+d][n'] = sum_m Ht[d][m]*SA[n'][m]
    gbt<64,128,2,2,0><<<dim3(1,4,CH), 256, 0, stream>>>(Ht, 32768, 512, SAb, 262144, 512,
                                                        nullptr, 0, SXt, 32768, 512, 512);
    // Gnd = transpose(c0/2*Ht + c1*T1t + c2*T2t + c3*T3t + SXt)
    k_combo<<<dim3(CH,8), 256, 0, stream>>>(Ht, T1t, T2t, T3t, SXt, coe, Gnd);
    // G2b[s0+cs][n*64+e] = bf16(leaky(Gnd[cs]*W1t^T + b1))  (K=64)
    gbt<128,64,2,2,5><<<dim3(4,1,CH), 256, 0, stream>>>(Gnd, 32768, 64, W1t, 0, 64,
                                                        b1, 0, G2b + (size_t)s0*32768, 32768, 64, 64);
  }

  // final: part[z] = G2b[:, z*1024:(z+1)*1024] @ Wlt[:, z*1024:(z+1)*1024]^T  (f32 partials)
  gbt<128,128,2,2,3><<<dim3(1,1,32), 256, 0, stream>>>(G2b, 1024, 32768, Wlt, 1024, 32768,
                                                       nullptr, 0, part, 16384, 128, 1024);
  // out = leaky(sum_z part + bl)
  k_final2<<<dim3(64), 256, 0, stream>>>(part, bl, out);
}

// Round 5
// 332.705 us; speedup vs baseline: 5.4087x; 1.1859x over previous
//
#include <hip/hip_runtime.h>
#include <math.h>

#define KORD 3
#ifndef M_PI
#define M_PI 3.14159265358979323846
#endif

typedef __attribute__((ext_vector_type(8))) __bf16 bf16x8;
typedef __attribute__((ext_vector_type(4))) float  f32x4;

__device__ __forceinline__ float leaky_(float v){ return v >= 0.f ? v : 0.01f*v; }

__device__ __forceinline__ f32x4 mfma16(bf16x8 a, bf16x8 b, f32x4 c){
  return __builtin_amdgcn_mfma_f32_16x16x32_bf16(a, b, c, 0, 0, 0);
}

// ---------------- Chebyshev coefficients ----------------
__global__ void k_coe(const float* __restrict__ temp, float* __restrict__ coe){
  if (threadIdx.x == 0 && blockIdx.x == 0){
    for (int i = 0; i <= KORD; ++i){
      float acc = 0.f;
      for (int j = 0; j <= KORD; ++j){
        double th = ((double)(KORD - j) + 0.5) * M_PI / (double)(KORD + 1);
        float t = temp[j]; t = t > 0.f ? t : 0.f;
        acc += t * (float)cos((double)i * th);
      }
      coe[i] = acc * (2.f / (float)(KORD + 1));
    }
  }
}

// ---------------- f32 -> bf16 convert ----------------
__global__ __launch_bounds__(256) void k_cvt(const float* __restrict__ in,
                                             __bf16* __restrict__ out, int n){
  int i = blockIdx.x*256 + threadIdx.x;
  if (i < n) out[i] = (__bf16)in[i];
}

// ---------------- W1t[e][d] = W1[d][e] (bf16) ----------------
__global__ __launch_bounds__(256) void k_w1t(const float* __restrict__ W1,
                                             __bf16* __restrict__ W1t){
  int t = threadIdx.x;
  for (int i = 0; i < 16; ++i){
    int e4 = i*256 + t;
    int e = e4 >> 6, d = e4 & 63;
    W1t[e*64 + d] = (__bf16)W1[d*64 + e];
  }
}

// ---------------- Wlt[o][k] = Wl[k][o] (bf16), Wl: [32768][128] ----------------
__global__ __launch_bounds__(256) void k_wlt(const float* __restrict__ Wl,
                                             __bf16* __restrict__ Wlt){
  __shared__ float Ls[64][65];
  int k0 = blockIdx.x*64, o0 = blockIdx.y*64;
  int t = threadIdx.x;
  for (int i = 0; i < 16; ++i){
    int e = i*256 + t; int r = e >> 6, c = e & 63;
    Ls[r][c] = Wl[(size_t)(k0 + r)*128 + o0 + c];
  }
  __syncthreads();
  for (int i = 0; i < 16; ++i){
    int e = i*256 + t; int r = e >> 6, c = e & 63;
    Wlt[(size_t)(o0 + r)*32768 + k0 + c] = (__bf16)Ls[c][r];
  }
}

// ---------------- bsaT[m][n] = bsa[n][m] (f32) ----------------
__global__ __launch_bounds__(256) void k_bsat(const float* __restrict__ bsa,
                                              float* __restrict__ bsaT){
  __shared__ float Ls[64][65];
  int n0 = blockIdx.x*64, m0 = blockIdx.y*64;
  int t = threadIdx.x;
  for (int i = 0; i < 16; ++i){
    int e = i*256 + t; int r = e >> 6, c = e & 63;
    Ls[r][c] = bsa[(size_t)(n0 + r)*512 + m0 + c];
  }
  __syncthreads();
  for (int i = 0; i < 16; ++i){
    int e = i*256 + t; int r = e >> 6, c = e & 63;
    bsaT[(size_t)(m0 + r)*512 + n0 + c] = Ls[c][r];
  }
}

// ---------------- embed both layouts: Ht[j][n] and Hnd[cs][n][d] ----------------
__global__ __launch_bounds__(256) void k_embed2(const float* __restrict__ x,
    const float* __restrict__ Wp, const float* __restrict__ bp,
    __bf16* __restrict__ Ht, __bf16* __restrict__ Hnd){
  __shared__ float Ls[64][65];
  int cs = blockIdx.x, n0 = blockIdx.y*64;
  int t = threadIdx.x;
  for (int i = 0; i < 16; ++i){
    int e = i*256 + t; int d = e >> 6, nn = e & 63;
    float v = x[cs*512 + n0 + nn]*Wp[d] + bp[d];
    Ls[d][nn] = v;
    Ht[(size_t)(cs*64 + d)*512 + n0 + nn] = (__bf16)v;
  }
  __syncthreads();
  for (int i = 0; i < 16; ++i){
    int e = i*256 + t; int nn = e >> 6, d = e & 63;
    Hnd[((size_t)cs*512 + n0 + nn)*64 + d] = (__bf16)Ls[d][nn];
  }
}

// ---------------- combo: Gnd[cs][n][d] = c0/2*H + c1*T1 + c2*T2 + c3*T3 + SX (transposed) ----------------
__global__ __launch_bounds__(256) void k_combo(const __bf16* __restrict__ Ht,
    const __bf16* __restrict__ T1t, const __bf16* __restrict__ T2t,
    const __bf16* __restrict__ T3t, const __bf16* __restrict__ SXt,
    const float* __restrict__ coe, __bf16* __restrict__ Gnd){
  __shared__ float Ls[64][65];
  int cs = blockIdx.x, n0 = blockIdx.y*64;
  int t = threadIdx.x;
  float c0 = coe[0]*0.5f, c1 = coe[1], c2 = coe[2], c3 = coe[3];
  for (int i = 0; i < 16; ++i){
    int e = i*256 + t; int d = e >> 6, nn = e & 63;
    size_t idx = (size_t)(cs*64 + d)*512 + n0 + nn;
    Ls[d][nn] = c0*(float)Ht[idx] + c1*(float)T1t[idx] + c2*(float)T2t[idx]
              + c3*(float)T3t[idx] + (float)SXt[idx];
  }
  __syncthreads();
  for (int i = 0; i < 16; ++i){
    int e = i*256 + t; int nn = e >> 6, d = e & 63;
    Gnd[((size_t)cs*512 + n0 + nn)*64 + d] = (__bf16)Ls[d][nn];
  }
}

// ---------------- MFMA GEMM: C[z] = A[z] * B[z]^T (+epilogue) ----------------
// EPI: 0 = bf16 out; 1 = bf16 out 2*acc - Z; 3 = f32 out; 5 = bf16 out leaky(acc + Ef[col])
template<int BM, int BN, int WM, int WN, int EPI>
__global__ __launch_bounds__(256) void gbt(
    const __bf16* __restrict__ A, size_t aB, int lda,
    const __bf16* __restrict__ B, size_t bB, int ldb,
    const void*  __restrict__ E, size_t eB,
    void* __restrict__ C, size_t cB, int ldc, int K){
  constexpr int WTM = BM/WM, WTN = BN/WN;
  constexpr int FM = WTM/16, FN = WTN/16;
  constexpr int LDK = 72;
  __shared__ __bf16 As[BM*LDK];
  __shared__ __bf16 Bs[BN*LDK];
  const int tid = threadIdx.x;
  const int wave = tid >> 6, lane = tid & 63;
  const int wm = wave % WM, wn = wave / WM;
  const int m0 = blockIdx.x*BM, n0 = blockIdx.y*BN;
  const int z = blockIdx.z;
  const __bf16* Ab = A + (size_t)z*aB + (size_t)m0*lda;
  const __bf16* Bb = B + (size_t)z*bB + (size_t)n0*ldb;
  f32x4 acc[FM][FN] = {};
  for (int k0 = 0; k0 < K; k0 += 64){
    __syncthreads();
    constexpr int AIT = BM*64/(256*8);
#pragma unroll
    for (int i = 0; i < AIT; ++i){
      int e = i*256 + tid; int r = e >> 3, c = (e & 7)*8;
      *(float4*)&As[r*LDK + c] = *(const float4*)&Ab[(size_t)r*lda + k0 + c];
    }
    constexpr int BIT = BN*64/(256*8);
#pragma unroll
    for (int i = 0; i < BIT; ++i){
      int e = i*256 + tid; int r = e >> 3, c = (e & 7)*8;
      *(float4*)&Bs[r*LDK + c] = *(const float4*)&Bb[(size_t)r*ldb + k0 + c];
    }
    __syncthreads();
#pragma unroll
    for (int ks = 0; ks < 2; ++ks){
      bf16x8 af[FM], bfr[FN];
      const int ko = ks*32 + (lane >> 4)*8;
#pragma unroll
      for (int i = 0; i < FM; ++i)
        af[i] = *(const bf16x8*)&As[(wm*WTM + i*16 + (lane & 15))*LDK + ko];
#pragma unroll
      for (int j = 0; j < FN; ++j)
        bfr[j] = *(const bf16x8*)&Bs[(wn*WTN + j*16 + (lane & 15))*LDK + ko];
#pragma unroll
      for (int i = 0; i < FM; ++i)
#pragma unroll
        for (int j = 0; j < FN; ++j)
          acc[i][j] = mfma16(af[i], bfr[j], acc[i][j]);
    }
  }
  __bf16* Cb = (__bf16*)C + (size_t)z*cB;
  float*  Cf = (float*)C  + (size_t)z*cB;
  const __bf16* Zb = (const __bf16*)E + (size_t)z*eB;
  const float*  Ef = (const float*)E;
  const int lr = (lane >> 4)*4, lc = lane & 15;
#pragma unroll
  for (int i = 0; i < FM; ++i){
    int row = m0 + wm*WTM + i*16 + lr;
#pragma unroll
    for (int j = 0; j < FN; ++j){
      int col = n0 + wn*WTN + j*16 + lc;
#pragma unroll
      for (int r = 0; r < 4; ++r){
        float v = acc[i][j][r];
        size_t idx = (size_t)(row + r)*ldc + col;
        if (EPI == 0){ Cb[idx] = (__bf16)v; }
        else if (EPI == 1){ Cb[idx] = (__bf16)(2.f*v - (float)Zb[idx]); }
        else if (EPI == 3){ Cf[idx] = v; }
        else if (EPI == 5){ float tt = v + Ef[col]; Cb[idx] = (__bf16)(tt >= 0.f ? tt : 0.01f*tt); }
      }
    }
  }
}

// ---------------- fused P+score: Sb[z][n][c] = bf16(sum_m Vsa[n][m]*tanh(sum_d Kx[c,d]h[m,d] + bsa[m,c])) ----------------
// grid (4,4,CH), block 256. P-tile generated in LDS per K-tile, never hits HBM.
__global__ __launch_bounds__(256) void k_score(
    const __bf16* __restrict__ Vsab,   // [512][512]
    const __bf16* __restrict__ KXnd,   // [z][512][64]
    const __bf16* __restrict__ Hnd,    // [z][512][64]
    const float*  __restrict__ bsaT,   // [512][512], bsaT[c][m] = bsa[m][c]
    __bf16* __restrict__ Sb){          // [z][512][512]
  constexpr int LDK = 72;
  __shared__ __bf16 KXs[128*LDK];  // c-tile of KX (persistent)
  __shared__ __bf16 Hs [64*LDK];   // m-tile of h
  __shared__ __bf16 Ps [128*LDK];  // P-tile [c][m]
  __shared__ __bf16 As [128*LDK];  // Vsa n-tile x m-tile
  const int tid = threadIdx.x, wave = tid >> 6, lane = tid & 63;
  const int wm = wave & 1, wn = wave >> 1;      // 2x2 wave grid
  const int lr = (lane >> 4)*4, lc = lane & 15;
  const int n0 = blockIdx.x*128, c0 = blockIdx.y*128;
  const int z = blockIdx.z;
  const __bf16* KXb = KXnd + (size_t)z*32768 + (size_t)c0*64;
  const __bf16* Hb  = Hnd  + (size_t)z*32768;
  const __bf16* Vb  = Vsab + (size_t)n0*512;
  // stage KX c-tile (128x64) once
#pragma unroll
  for (int i = 0; i < 4; ++i){
    int e = i*256 + tid; int r = e >> 3, c = (e & 7)*8;
    *(float4*)&KXs[r*LDK + c] = *(const float4*)&KXb[(size_t)r*64 + c];
  }
  f32x4 acc[4][4] = {};
  for (int m0 = 0; m0 < 512; m0 += 64){
    __syncthreads();   // Hs/As (and KXs on iter 0) ready-to-overwrite / first use
    // stage h m-tile (64x64) and Vsa n-tile x m-tile (128x64)
#pragma unroll
    for (int i = 0; i < 2; ++i){
      int e = i*256 + tid; int r = e >> 3, c = (e & 7)*8;
      *(float4*)&Hs[r*LDK + c] = *(const float4*)&Hb[(size_t)(m0 + r)*64 + c];
    }
#pragma unroll
    for (int i = 0; i < 4; ++i){
      int e = i*256 + tid; int r = e >> 3, c = (e & 7)*8;
      *(float4*)&As[r*LDK + c] = *(const float4*)&Vb[(size_t)r*512 + m0 + c];
    }
    __syncthreads();
    // sub-GEMM: P[c 128][m 64] = tanh(KXs * Hs^T + bsaT); waves: wm->c (64), wn->m (32)
    f32x4 pacc[4][2];
#pragma unroll
    for (int i = 0; i < 4; ++i)
#pragma unroll
      for (int j = 0; j < 2; ++j)
#pragma unroll
        for (int r = 0; r < 4; ++r)
          pacc[i][j][r] = bsaT[(size_t)(c0 + wm*64 + i*16 + lr + r)*512
                               + m0 + wn*32 + j*16 + lc];
#pragma unroll
    for (int ks = 0; ks < 2; ++ks){
      const int ko = ks*32 + (lane >> 4)*8;
      bf16x8 ka[4], hb[2];
#pragma unroll
      for (int i = 0; i < 4; ++i)
        ka[i] = *(const bf16x8*)&KXs[(wm*64 + i*16 + (lane & 15))*LDK + ko];
#pragma unroll
      for (int j = 0; j < 2; ++j)
        hb[j] = *(const bf16x8*)&Hs[(wn*32 + j*16 + (lane & 15))*LDK + ko];
#pragma unroll
      for (int i = 0; i < 4; ++i)
#pragma unroll
        for (int j = 0; j < 2; ++j)
          pacc[i][j] = mfma16(ka[i], hb[j], pacc[i][j]);
    }
#pragma unroll
    for (int i = 0; i < 4; ++i)
#pragma unroll
      for (int j = 0; j < 2; ++j)
#pragma unroll
        for (int r = 0; r < 4; ++r)
          Ps[(wm*64 + i*16 + lr + r)*LDK + wn*32 + j*16 + lc] = (__bf16)tanhf(pacc[i][j][r]);
    __syncthreads();
    // main: acc[n 128][c 128] += As(Vsa) * Ps^T ; waves: wm->n (64), wn->c (64)
#pragma unroll
    for (int ks = 0; ks < 2; ++ks){
      const int ko = ks*32 + (lane >> 4)*8;
      bf16x8 af[4], bfr[4];
#pragma unroll
      for (int i = 0; i < 4; ++i)
        af[i] = *(const bf16x8*)&As[(wm*64 + i*16 + (lane & 15))*LDK + ko];
#pragma unroll
      for (int j = 0; j < 4; ++j)
        bfr[j] = *(const bf16x8*)&Ps[(wn*64 + j*16 + (lane & 15))*LDK + ko];
#pragma unroll
      for (int i = 0; i < 4; ++i)
#pragma unroll
        for (int j = 0; j < 4; ++j)
          acc[i][j] = mfma16(af[i], bfr[j], acc[i][j]);
    }
  }
  __bf16* Cb = Sb + (size_t)z*262144;
#pragma unroll
  for (int i = 0; i < 4; ++i){
    int row = n0 + wm*64 + i*16 + lr;
#pragma unroll
    for (int j = 0; j < 4; ++j){
      int col = c0 + wn*64 + j*16 + lc;
#pragma unroll
      for (int r = 0; r < 4; ++r)
        Cb[(size_t)(row + r)*512 + col] = (__bf16)acc[i][j][r];
    }
  }
}

// ---------------- softmax rows of 512, bf16 in-place ----------------
__global__ __launch_bounds__(256) void k_softmax(__bf16* __restrict__ S){
  int row  = blockIdx.x*4 + (threadIdx.x >> 6);
  int lane = threadIdx.x & 63;
  __bf16* p = S + (size_t)row*512;
  bf16x8 v = ((bf16x8*)p)[lane];
  float f[8];
#pragma unroll
  for (int j = 0; j < 8; ++j) f[j] = (float)v[j];
  float mx = f[0];
#pragma unroll
  for (int j = 1; j < 8; ++j) mx = fmaxf(mx, f[j]);
#pragma unroll
  for (int m = 1; m < 64; m <<= 1) mx = fmaxf(mx, __shfl_xor(mx, m, 64));
  float s = 0.f;
#pragma unroll
  for (int j = 0; j < 8; ++j){ f[j] = expf(f[j] - mx); s += f[j]; }
#pragma unroll
  for (int m = 1; m < 64; m <<= 1) s += __shfl_xor(s, m, 64);
  float r = 1.f / s;
#pragma unroll
  for (int j = 0; j < 8; ++j) v[j] = (__bf16)(f[j]*r);
  ((bf16x8*)p)[lane] = v;
}

// ---------------- reduce 32 K-partials + bias + leaky ----------------
__global__ __launch_bounds__(256) void k_final2(
    const float* __restrict__ part, const float* __restrict__ bl,
    float* __restrict__ out){
  int idx = blockIdx.x*256 + threadIdx.x;
  int o = idx & 127;
  float acc = bl[o];
#pragma unroll
  for (int p = 0; p < 32; ++p) acc += part[(size_t)p*16384 + idx];
  out[idx] = leaky_(acc);
}

extern "C" void kernel_launch(void* const* d_in, const int* in_sizes, int n_in,
                              void* d_out, int out_size, void* d_ws, size_t ws_size,
                              hipStream_t stream){
  const float* x    = (const float*)d_in[0];
  const float* adj  = (const float*)d_in[1];
  const float* Wp   = (const float*)d_in[2];
  const float* bp   = (const float*)d_in[3];
  const float* Ksa  = (const float*)d_in[4];
  const float* Vsa  = (const float*)d_in[5];
  const float* bsa  = (const float*)d_in[6];
  const float* temp = (const float*)d_in[7];
  const float* W1   = (const float*)d_in[8];
  const float* b1   = (const float*)d_in[9];
  const float* Wl   = (const float*)d_in[10];
  const float* bl   = (const float*)d_in[11];
  float* out = (float*)d_out;

  // ---- workspace carve-up (bytes), chunk-adaptive ----
  char* ws = (char*)d_ws;
  size_t off = 0;
  auto alloc = [&](size_t bytes){ void* p = ws + off; off += (bytes + 255) & ~(size_t)255; return p; };
  float*  coe  = (float*)alloc(64);
  __bf16* G2b  = (__bf16*)alloc((size_t)128*32768*2);   // 8.4 MB
  __bf16* Wlt  = (__bf16*)alloc((size_t)128*32768*2);   // 8.4 MB
  float*  part = (float*)alloc((size_t)32*16384*4);     // 2.1 MB
  float*  bsaT = (float*)alloc((size_t)512*512*4);      // 1 MB
  __bf16* adjb = (__bf16*)alloc((size_t)512*512*2);
  __bf16* Ksab = (__bf16*)alloc((size_t)512*512*2);
  __bf16* Vsab = (__bf16*)alloc((size_t)512*512*2);
  __bf16* W1t  = (__bf16*)alloc((size_t)64*64*2);
  const size_t fixedOff = off;

  // per-slice: 8 bf16 [64x512] bufs (512KB) + Sb bf16 [512][512] (512KB) = 1 MB
  int CH = 128;
  while (CH > 2){
    size_t need = fixedOff + (size_t)CH*(8*65536 + 524288) + 65536;
    if (need <= ws_size) break;
    CH >>= 1;
  }
  __bf16* Ht   = (__bf16*)alloc((size_t)CH*65536);
  __bf16* T1t  = (__bf16*)alloc((size_t)CH*65536);
  __bf16* T2t  = (__bf16*)alloc((size_t)CH*65536);
  __bf16* T3t  = (__bf16*)alloc((size_t)CH*65536);
  __bf16* KXnd = (__bf16*)alloc((size_t)CH*65536);
  __bf16* Hnd  = (__bf16*)alloc((size_t)CH*65536);
  __bf16* SXt  = (__bf16*)alloc((size_t)CH*65536);
  __bf16* Gnd  = (__bf16*)alloc((size_t)CH*65536);
  __bf16* Sb   = (__bf16*)alloc((size_t)CH*524288);

  // preprocessing
  k_coe<<<1, 64, 0, stream>>>(temp, coe);
  k_cvt<<<1024, 256, 0, stream>>>(adj, adjb, 512*512);
  k_cvt<<<1024, 256, 0, stream>>>(Ksa, Ksab, 512*512);
  k_cvt<<<1024, 256, 0, stream>>>(Vsa, Vsab, 512*512);
  k_w1t<<<1, 256, 0, stream>>>(W1, W1t);
  k_wlt<<<dim3(512,2), 256, 0, stream>>>(Wl, Wlt);
  k_bsat<<<dim3(8,8), 256, 0, stream>>>(bsa, bsaT);

  for (int s0 = 0; s0 < 128; s0 += CH){
    // embed both layouts
    k_embed2<<<dim3(CH,8), 256, 0, stream>>>(x + (size_t)s0*512, Wp, bp, Ht, Hnd);
    // Chebyshev (j-major): T1t = Ht*adj^T ; T2t = 2*T1t*adj^T - Ht ; T3t = 2*T2t*adj^T - T1t
    gbt<128,128,2,2,0><<<dim3(CH/2,4,1), 256, 0, stream>>>(Ht, 0, 512, adjb, 0, 512, nullptr, 0, T1t, 0, 512, 512);
    gbt<128,128,2,2,1><<<dim3(CH/2,4,1), 256, 0, stream>>>(T1t, 0, 512, adjb, 0, 512, Ht, 0, T2t, 0, 512, 512);
    gbt<128,128,2,2,1><<<dim3(CH/2,4,1), 256, 0, stream>>>(T2t, 0, 512, adjb, 0, 512, T1t, 0, T3t, 0, 512, 512);
    // KXnd[cs][m][d] = Ksa @ H
    gbt<128,64,2,2,0><<<dim3(4,1,CH), 256, 0, stream>>>(Ksab, 0, 512, Ht, 32768, 512,
                                                        nullptr, 0, KXnd, 32768, 64, 512);
    // fused P+score -> Sb bf16
    k_score<<<dim3(4,4,CH), 256, 0, stream>>>(Vsab, KXnd, Hnd, bsaT, Sb);
    // softmax rows, bf16 in-place
    k_softmax<<<dim3(CH*128), 256, 0, stream>>>(Sb);
    // SXt[cs*64+d][n'] = sum_m Ht[d][m]*SA[n'][m]
    gbt<64,128,2,2,0><<<dim3(1,4,CH), 256, 0, stream>>>(Ht, 32768, 512, Sb, 262144, 512,
                                                        nullptr, 0, SXt, 32768, 512, 512);
    // Gnd = transpose(c0/2*Ht + c1*T1t + c2*T2t + c3*T3t + SXt)
    k_combo<<<dim3(CH,8), 256, 0, stream>>>(Ht, T1t, T2t, T3t, SXt, coe, Gnd);
    // G2b[s0+cs][n*64+e] = bf16(leaky(Gnd[cs]*W1t^T + b1))
    gbt<128,64,2,2,5><<<dim3(4,1,CH), 256, 0, stream>>>(Gnd, 32768, 64, W1t, 0, 64,
                                                        b1, 0, G2b + (size_t)s0*32768, 32768, 64, 64);
  }

  // final: part[z] = G2b[:, z*1024:(z+1)*1024] @ Wlt[:, z*1024:(z+1)*1024]^T
  gbt<128,128,2,2,3><<<dim3(1,1,32), 256, 0, stream>>>(G2b, 1024, 32768, Wlt, 1024, 32768,
                                                       nullptr, 0, part, 16384, 128, 1024);
  // out = leaky(sum_z part + bl)
  k_final2<<<dim3(64), 256, 0, stream>>>(part, bl, out);
}

// Round 6
// 323.377 us; speedup vs baseline: 5.5647x; 1.0288x over previous
//
#include <hip/hip_runtime.h>
#include <math.h>

#define KORD 3
#ifndef M_PI
#define M_PI 3.14159265358979323846
#endif

typedef __attribute__((ext_vector_type(8))) __bf16 bf16x8;
typedef __attribute__((ext_vector_type(4))) float  f32x4;

__device__ __forceinline__ float leaky_(float v){ return v >= 0.f ? v : 0.01f*v; }

__device__ __forceinline__ float tanh_fast(float x){
  // clamp: tanh(+-10) == +-1.0f to f32 precision; avoids inf/inf
  float xc = fminf(fmaxf(x, -10.f), 10.f);
  float t = __expf(2.f*xc);          // v_exp_f32 path
  return (t - 1.f) / (t + 1.f);      // v_rcp_f32 + mul
}

__device__ __forceinline__ f32x4 mfma16(bf16x8 a, bf16x8 b, f32x4 c){
  return __builtin_amdgcn_mfma_f32_16x16x32_bf16(a, b, c, 0, 0, 0);
}

// ---------------- Chebyshev coefficients ----------------
__global__ void k_coe(const float* __restrict__ temp, float* __restrict__ coe){
  if (threadIdx.x == 0 && blockIdx.x == 0){
    for (int i = 0; i <= KORD; ++i){
      float acc = 0.f;
      for (int j = 0; j <= KORD; ++j){
        double th = ((double)(KORD - j) + 0.5) * M_PI / (double)(KORD + 1);
        float t = temp[j]; t = t > 0.f ? t : 0.f;
        acc += t * (float)cos((double)i * th);
      }
      coe[i] = acc * (2.f / (float)(KORD + 1));
    }
  }
}

// ---------------- f32 -> bf16 convert ----------------
__global__ __launch_bounds__(256) void k_cvt(const float* __restrict__ in,
                                             __bf16* __restrict__ out, int n){
  int i = blockIdx.x*256 + threadIdx.x;
  if (i < n) out[i] = (__bf16)in[i];
}

// ---------------- W1t[e][d] = W1[d][e] (bf16) ----------------
__global__ __launch_bounds__(256) void k_w1t(const float* __restrict__ W1,
                                             __bf16* __restrict__ W1t){
  int t = threadIdx.x;
  for (int i = 0; i < 16; ++i){
    int e4 = i*256 + t;
    int e = e4 >> 6, d = e4 & 63;
    W1t[e*64 + d] = (__bf16)W1[d*64 + e];
  }
}

// ---------------- Wlt[o][k] = Wl[k][o] (bf16), Wl: [32768][128] ----------------
__global__ __launch_bounds__(256) void k_wlt(const float* __restrict__ Wl,
                                             __bf16* __restrict__ Wlt){
  __shared__ float Ls[64][65];
  int k0 = blockIdx.x*64, o0 = blockIdx.y*64;
  int t = threadIdx.x;
  for (int i = 0; i < 16; ++i){
    int e = i*256 + t; int r = e >> 6, c = e & 63;
    Ls[r][c] = Wl[(size_t)(k0 + r)*128 + o0 + c];
  }
  __syncthreads();
  for (int i = 0; i < 16; ++i){
    int e = i*256 + t; int r = e >> 6, c = e & 63;
    Wlt[(size_t)(o0 + r)*32768 + k0 + c] = (__bf16)Ls[c][r];
  }
}

// ---------------- bsaT[m][n] = bsa[n][m] (f32) ----------------
__global__ __launch_bounds__(256) void k_bsat(const float* __restrict__ bsa,
                                              float* __restrict__ bsaT){
  __shared__ float Ls[64][65];
  int n0 = blockIdx.x*64, m0 = blockIdx.y*64;
  int t = threadIdx.x;
  for (int i = 0; i < 16; ++i){
    int e = i*256 + t; int r = e >> 6, c = e & 63;
    Ls[r][c] = bsa[(size_t)(n0 + r)*512 + m0 + c];
  }
  __syncthreads();
  for (int i = 0; i < 16; ++i){
    int e = i*256 + t; int r = e >> 6, c = e & 63;
    bsaT[(size_t)(m0 + r)*512 + n0 + c] = Ls[c][r];
  }
}

// ---------------- embed both layouts: Ht[j][n] and Hnd[cs][n][d] ----------------
__global__ __launch_bounds__(256) void k_embed2(const float* __restrict__ x,
    const float* __restrict__ Wp, const float* __restrict__ bp,
    __bf16* __restrict__ Ht, __bf16* __restrict__ Hnd){
  __shared__ float Ls[64][65];
  int cs = blockIdx.x, n0 = blockIdx.y*64;
  int t = threadIdx.x;
  for (int i = 0; i < 16; ++i){
    int e = i*256 + t; int d = e >> 6, nn = e & 63;
    float v = x[cs*512 + n0 + nn]*Wp[d] + bp[d];
    Ls[d][nn] = v;
    Ht[(size_t)(cs*64 + d)*512 + n0 + nn] = (__bf16)v;
  }
  __syncthreads();
  for (int i = 0; i < 16; ++i){
    int e = i*256 + t; int nn = e >> 6, d = e & 63;
    Hnd[((size_t)cs*512 + n0 + nn)*64 + d] = (__bf16)Ls[d][nn];
  }
}

// ---------------- combo: Gnd[cs][n][d] = c0/2*H + c1*T1 + c2*T2 + c3*T3 + SX (transposed) ----------------
__global__ __launch_bounds__(256) void k_combo(const __bf16* __restrict__ Ht,
    const __bf16* __restrict__ T1t, const __bf16* __restrict__ T2t,
    const __bf16* __restrict__ T3t, const __bf16* __restrict__ SXt,
    const float* __restrict__ coe, __bf16* __restrict__ Gnd){
  __shared__ float Ls[64][65];
  int cs = blockIdx.x, n0 = blockIdx.y*64;
  int t = threadIdx.x;
  float c0 = coe[0]*0.5f, c1 = coe[1], c2 = coe[2], c3 = coe[3];
  for (int i = 0; i < 16; ++i){
    int e = i*256 + t; int d = e >> 6, nn = e & 63;
    size_t idx = (size_t)(cs*64 + d)*512 + n0 + nn;
    Ls[d][nn] = c0*(float)Ht[idx] + c1*(float)T1t[idx] + c2*(float)T2t[idx]
              + c3*(float)T3t[idx] + (float)SXt[idx];
  }
  __syncthreads();
  for (int i = 0; i < 16; ++i){
    int e = i*256 + t; int nn = e >> 6, d = e & 63;
    Gnd[((size_t)cs*512 + n0 + nn)*64 + d] = (__bf16)Ls[d][nn];
  }
}

// ---------------- MFMA GEMM: C[z] = A[z] * B[z]^T (+epilogue) ----------------
// EPI: 0 = bf16 out; 1 = bf16 out 2*acc - Z; 3 = f32 out; 5 = bf16 out leaky(acc + Ef[col])
template<int BM, int BN, int WM, int WN, int EPI>
__global__ __launch_bounds__(256) void gbt(
    const __bf16* __restrict__ A, size_t aB, int lda,
    const __bf16* __restrict__ B, size_t bB, int ldb,
    const void*  __restrict__ E, size_t eB,
    void* __restrict__ C, size_t cB, int ldc, int K){
  constexpr int WTM = BM/WM, WTN = BN/WN;
  constexpr int FM = WTM/16, FN = WTN/16;
  constexpr int LDK = 72;
  __shared__ __bf16 As[BM*LDK];
  __shared__ __bf16 Bs[BN*LDK];
  const int tid = threadIdx.x;
  const int wave = tid >> 6, lane = tid & 63;
  const int wm = wave % WM, wn = wave / WM;
  const int m0 = blockIdx.x*BM, n0 = blockIdx.y*BN;
  const int z = blockIdx.z;
  const __bf16* Ab = A + (size_t)z*aB + (size_t)m0*lda;
  const __bf16* Bb = B + (size_t)z*bB + (size_t)n0*ldb;
  f32x4 acc[FM][FN] = {};
  for (int k0 = 0; k0 < K; k0 += 64){
    __syncthreads();
    constexpr int AIT = BM*64/(256*8);
#pragma unroll
    for (int i = 0; i < AIT; ++i){
      int e = i*256 + tid; int r = e >> 3, c = (e & 7)*8;
      *(float4*)&As[r*LDK + c] = *(const float4*)&Ab[(size_t)r*lda + k0 + c];
    }
    constexpr int BIT = BN*64/(256*8);
#pragma unroll
    for (int i = 0; i < BIT; ++i){
      int e = i*256 + tid; int r = e >> 3, c = (e & 7)*8;
      *(float4*)&Bs[r*LDK + c] = *(const float4*)&Bb[(size_t)r*ldb + k0 + c];
    }
    __syncthreads();
#pragma unroll
    for (int ks = 0; ks < 2; ++ks){
      bf16x8 af[FM], bfr[FN];
      const int ko = ks*32 + (lane >> 4)*8;
#pragma unroll
      for (int i = 0; i < FM; ++i)
        af[i] = *(const bf16x8*)&As[(wm*WTM + i*16 + (lane & 15))*LDK + ko];
#pragma unroll
      for (int j = 0; j < FN; ++j)
        bfr[j] = *(const bf16x8*)&Bs[(wn*WTN + j*16 + (lane & 15))*LDK + ko];
#pragma unroll
      for (int i = 0; i < FM; ++i)
#pragma unroll
        for (int j = 0; j < FN; ++j)
          acc[i][j] = mfma16(af[i], bfr[j], acc[i][j]);
    }
  }
  __bf16* Cb = (__bf16*)C + (size_t)z*cB;
  float*  Cf = (float*)C  + (size_t)z*cB;
  const __bf16* Zb = (const __bf16*)E + (size_t)z*eB;
  const float*  Ef = (const float*)E;
  const int lr = (lane >> 4)*4, lc = lane & 15;
#pragma unroll
  for (int i = 0; i < FM; ++i){
    int row = m0 + wm*WTM + i*16 + lr;
#pragma unroll
    for (int j = 0; j < FN; ++j){
      int col = n0 + wn*WTN + j*16 + lc;
#pragma unroll
      for (int r = 0; r < 4; ++r){
        float v = acc[i][j][r];
        size_t idx = (size_t)(row + r)*ldc + col;
        if (EPI == 0){ Cb[idx] = (__bf16)v; }
        else if (EPI == 1){ Cb[idx] = (__bf16)(2.f*v - (float)Zb[idx]); }
        else if (EPI == 3){ Cf[idx] = v; }
        else if (EPI == 5){ float tt = v + Ef[col]; Cb[idx] = (__bf16)(tt >= 0.f ? tt : 0.01f*tt); }
      }
    }
  }
}

// ---------------- fused P+score: Sb[z][n][c] = bf16(sum_m Vsa[n][m]*tanh(sum_d Kx[c,d]h[m,d] + bsa[m,c])) ----------------
__global__ __launch_bounds__(256) void k_score(
    const __bf16* __restrict__ Vsab,   // [512][512]
    const __bf16* __restrict__ KXnd,   // [z][512][64]
    const __bf16* __restrict__ Hnd,    // [z][512][64]
    const float*  __restrict__ bsaT,   // [512][512], bsaT[c][m] = bsa[m][c]
    __bf16* __restrict__ Sb){          // [z][512][512]
  constexpr int LDK = 72;
  __shared__ __bf16 KXs[128*LDK];  // c-tile of KX (persistent)
  __shared__ __bf16 Hs [64*LDK];   // m-tile of h
  __shared__ __bf16 Ps [128*LDK];  // P-tile [c][m]
  __shared__ __bf16 As [128*LDK];  // Vsa n-tile x m-tile
  const int tid = threadIdx.x, wave = tid >> 6, lane = tid & 63;
  const int wm = wave & 1, wn = wave >> 1;      // 2x2 wave grid
  const int lr = (lane >> 4)*4, lc = lane & 15;
  const int n0 = blockIdx.x*128, c0 = blockIdx.y*128;
  const int z = blockIdx.z;
  const __bf16* KXb = KXnd + (size_t)z*32768 + (size_t)c0*64;
  const __bf16* Hb  = Hnd  + (size_t)z*32768;
  const __bf16* Vb  = Vsab + (size_t)n0*512;
  // stage KX c-tile (128x64) once
#pragma unroll
  for (int i = 0; i < 4; ++i){
    int e = i*256 + tid; int r = e >> 3, c = (e & 7)*8;
    *(float4*)&KXs[r*LDK + c] = *(const float4*)&KXb[(size_t)r*64 + c];
  }
  f32x4 acc[4][4] = {};
  for (int m0 = 0; m0 < 512; m0 += 64){
    __syncthreads();
    // stage h m-tile (64x64) and Vsa n-tile x m-tile (128x64)
#pragma unroll
    for (int i = 0; i < 2; ++i){
      int e = i*256 + tid; int r = e >> 3, c = (e & 7)*8;
      *(float4*)&Hs[r*LDK + c] = *(const float4*)&Hb[(size_t)(m0 + r)*64 + c];
    }
#pragma unroll
    for (int i = 0; i < 4; ++i){
      int e = i*256 + tid; int r = e >> 3, c = (e & 7)*8;
      *(float4*)&As[r*LDK + c] = *(const float4*)&Vb[(size_t)r*512 + m0 + c];
    }
    __syncthreads();
    // sub-GEMM: P[c 128][m 64] = tanh(KXs * Hs^T + bsaT); waves: wm->c (64), wn->m (32)
    f32x4 pacc[4][2];
#pragma unroll
    for (int i = 0; i < 4; ++i)
#pragma unroll
      for (int j = 0; j < 2; ++j)
#pragma unroll
        for (int r = 0; r < 4; ++r)
          pacc[i][j][r] = bsaT[(size_t)(c0 + wm*64 + i*16 + lr + r)*512
                               + m0 + wn*32 + j*16 + lc];
#pragma unroll
    for (int ks = 0; ks < 2; ++ks){
      const int ko = ks*32 + (lane >> 4)*8;
      bf16x8 ka[4], hb[2];
#pragma unroll
      for (int i = 0; i < 4; ++i)
        ka[i] = *(const bf16x8*)&KXs[(wm*64 + i*16 + (lane & 15))*LDK + ko];
#pragma unroll
      for (int j = 0; j < 2; ++j)
        hb[j] = *(const bf16x8*)&Hs[(wn*32 + j*16 + (lane & 15))*LDK + ko];
#pragma unroll
      for (int i = 0; i < 4; ++i)
#pragma unroll
        for (int j = 0; j < 2; ++j)
          pacc[i][j] = mfma16(ka[i], hb[j], pacc[i][j]);
    }
#pragma unroll
    for (int i = 0; i < 4; ++i)
#pragma unroll
      for (int j = 0; j < 2; ++j)
#pragma unroll
        for (int r = 0; r < 4; ++r)
          Ps[(wm*64 + i*16 + lr + r)*LDK + wn*32 + j*16 + lc] = (__bf16)tanh_fast(pacc[i][j][r]);
    __syncthreads();
    // main: acc[n 128][c 128] += As(Vsa) * Ps^T ; waves: wm->n (64), wn->c (64)
#pragma unroll
    for (int ks = 0; ks < 2; ++ks){
      const int ko = ks*32 + (lane >> 4)*8;
      bf16x8 af[4], bfr[4];
#pragma unroll
      for (int i = 0; i < 4; ++i)
        af[i] = *(const bf16x8*)&As[(wm*64 + i*16 + (lane & 15))*LDK + ko];
#pragma unroll
      for (int j = 0; j < 4; ++j)
        bfr[j] = *(const bf16x8*)&Ps[(wn*64 + j*16 + (lane & 15))*LDK + ko];
#pragma unroll
      for (int i = 0; i < 4; ++i)
#pragma unroll
        for (int j = 0; j < 4; ++j)
          acc[i][j] = mfma16(af[i], bfr[j], acc[i][j]);
    }
  }
  __bf16* Cb = Sb + (size_t)z*262144;
#pragma unroll
  for (int i = 0; i < 4; ++i){
    int row = n0 + wm*64 + i*16 + lr;
#pragma unroll
    for (int j = 0; j < 4; ++j){
      int col = c0 + wn*64 + j*16 + lc;
#pragma unroll
      for (int r = 0; r < 4; ++r)
        Cb[(size_t)(row + r)*512 + col] = (__bf16)acc[i][j][r];
    }
  }
}

// ---------------- softmax rows of 512, bf16 in-place ----------------
__global__ __launch_bounds__(256) void k_softmax(__bf16* __restrict__ S){
  int row  = blockIdx.x*4 + (threadIdx.x >> 6);
  int lane = threadIdx.x & 63;
  __bf16* p = S + (size_t)row*512;
  bf16x8 v = ((bf16x8*)p)[lane];
  float f[8];
#pragma unroll
  for (int j = 0; j < 8; ++j) f[j] = (float)v[j];
  float mx = f[0];
#pragma unroll
  for (int j = 1; j < 8; ++j) mx = fmaxf(mx, f[j]);
#pragma unroll
  for (int m = 1; m < 64; m <<= 1) mx = fmaxf(mx, __shfl_xor(mx, m, 64));
  float s = 0.f;
#pragma unroll
  for (int j = 0; j < 8; ++j){ f[j] = __expf(f[j] - mx); s += f[j]; }
#pragma unroll
  for (int m = 1; m < 64; m <<= 1) s += __shfl_xor(s, m, 64);
  float r = 1.f / s;
#pragma unroll
  for (int j = 0; j < 8; ++j) v[j] = (__bf16)(f[j]*r);
  ((bf16x8*)p)[lane] = v;
}

// ---------------- reduce 32 K-partials + bias + leaky ----------------
__global__ __launch_bounds__(256) void k_final2(
    const float* __restrict__ part, const float* __restrict__ bl,
    float* __restrict__ out){
  int idx = blockIdx.x*256 + threadIdx.x;
  int o = idx & 127;
  float acc = bl[o];
#pragma unroll
  for (int p = 0; p < 32; ++p) acc += part[(size_t)p*16384 + idx];
  out[idx] = leaky_(acc);
}

extern "C" void kernel_launch(void* const* d_in, const int* in_sizes, int n_in,
                              void* d_out, int out_size, void* d_ws, size_t ws_size,
                              hipStream_t stream){
  const float* x    = (const float*)d_in[0];
  const float* adj  = (const float*)d_in[1];
  const float* Wp   = (const float*)d_in[2];
  const float* bp   = (const float*)d_in[3];
  const float* Ksa  = (const float*)d_in[4];
  const float* Vsa  = (const float*)d_in[5];
  const float* bsa  = (const float*)d_in[6];
  const float* temp = (const float*)d_in[7];
  const float* W1   = (const float*)d_in[8];
  const float* b1   = (const float*)d_in[9];
  const float* Wl   = (const float*)d_in[10];
  const float* bl   = (const float*)d_in[11];
  float* out = (float*)d_out;

  // ---- workspace carve-up (bytes), chunk-adaptive ----
  char* ws = (char*)d_ws;
  size_t off = 0;
  auto alloc = [&](size_t bytes){ void* p = ws + off; off += (bytes + 255) & ~(size_t)255; return p; };
  float*  coe  = (float*)alloc(64);
  __bf16* G2b  = (__bf16*)alloc((size_t)128*32768*2);   // 8.4 MB
  __bf16* Wlt  = (__bf16*)alloc((size_t)128*32768*2);   // 8.4 MB
  float*  part = (float*)alloc((size_t)32*16384*4);     // 2.1 MB
  float*  bsaT = (float*)alloc((size_t)512*512*4);      // 1 MB
  __bf16* adjb = (__bf16*)alloc((size_t)512*512*2);
  __bf16* Ksab = (__bf16*)alloc((size_t)512*512*2);
  __bf16* Vsab = (__bf16*)alloc((size_t)512*512*2);
  __bf16* W1t  = (__bf16*)alloc((size_t)64*64*2);
  const size_t fixedOff = off;

  // per-slice: 8 bf16 [64x512] bufs (512KB) + Sb bf16 [512][512] (512KB) = 1 MB
  int CH = 128;
  while (CH > 2){
    size_t need = fixedOff + (size_t)CH*(8*65536 + 524288) + 65536;
    if (need <= ws_size) break;
    CH >>= 1;
  }
  __bf16* Ht   = (__bf16*)alloc((size_t)CH*65536);
  __bf16* T1t  = (__bf16*)alloc((size_t)CH*65536);
  __bf16* T2t  = (__bf16*)alloc((size_t)CH*65536);
  __bf16* T3t  = (__bf16*)alloc((size_t)CH*65536);
  __bf16* KXnd = (__bf16*)alloc((size_t)CH*65536);
  __bf16* Hnd  = (__bf16*)alloc((size_t)CH*65536);
  __bf16* SXt  = (__bf16*)alloc((size_t)CH*65536);
  __bf16* Gnd  = (__bf16*)alloc((size_t)CH*65536);
  __bf16* Sb   = (__bf16*)alloc((size_t)CH*524288);

  // preprocessing
  k_coe<<<1, 64, 0, stream>>>(temp, coe);
  k_cvt<<<1024, 256, 0, stream>>>(adj, adjb, 512*512);
  k_cvt<<<1024, 256, 0, stream>>>(Ksa, Ksab, 512*512);
  k_cvt<<<1024, 256, 0, stream>>>(Vsa, Vsab, 512*512);
  k_w1t<<<1, 256, 0, stream>>>(W1, W1t);
  k_wlt<<<dim3(512,2), 256, 0, stream>>>(Wl, Wlt);
  k_bsat<<<dim3(8,8), 256, 0, stream>>>(bsa, bsaT);

  for (int s0 = 0; s0 < 128; s0 += CH){
    // embed both layouts
    k_embed2<<<dim3(CH,8), 256, 0, stream>>>(x + (size_t)s0*512, Wp, bp, Ht, Hnd);
    // Chebyshev (j-major): T1t = Ht*adj^T ; T2t = 2*T1t*adj^T - Ht ; T3t = 2*T2t*adj^T - T1t
    gbt<128,128,2,2,0><<<dim3(CH/2,4,1), 256, 0, stream>>>(Ht, 0, 512, adjb, 0, 512, nullptr, 0, T1t, 0, 512, 512);
    gbt<128,128,2,2,1><<<dim3(CH/2,4,1), 256, 0, stream>>>(T1t, 0, 512, adjb, 0, 512, Ht, 0, T2t, 0, 512, 512);
    gbt<128,128,2,2,1><<<dim3(CH/2,4,1), 256, 0, stream>>>(T2t, 0, 512, adjb, 0, 512, T1t, 0, T3t, 0, 512, 512);
    // KXnd[cs][m][d] = Ksa @ H
    gbt<128,64,2,2,0><<<dim3(4,1,CH), 256, 0, stream>>>(Ksab, 0, 512, Ht, 32768, 512,
                                                        nullptr, 0, KXnd, 32768, 64, 512);
    // fused P+score -> Sb bf16
    k_score<<<dim3(4,4,CH), 256, 0, stream>>>(Vsab, KXnd, Hnd, bsaT, Sb);
    // softmax rows, bf16 in-place
    k_softmax<<<dim3(CH*128), 256, 0, stream>>>(Sb);
    // SXt[cs*64+d][n'] = sum_m Ht[d][m]*SA[n'][m]
    gbt<64,128,2,2,0><<<dim3(1,4,CH), 256, 0, stream>>>(Ht, 32768, 512, Sb, 262144, 512,
                                                        nullptr, 0, SXt, 32768, 512, 512);
    // Gnd = transpose(c0/2*Ht + c1*T1t + c2*T2t + c3*T3t + SXt)
    k_combo<<<dim3(CH,8), 256, 0, stream>>>(Ht, T1t, T2t, T3t, SXt, coe, Gnd);
    // G2b[s0+cs][n*64+e] = bf16(leaky(Gnd[cs]*W1t^T + b1))
    gbt<128,64,2,2,5><<<dim3(4,1,CH), 256, 0, stream>>>(Gnd, 32768, 64, W1t, 0, 64,
                                                        b1, 0, G2b + (size_t)s0*32768, 32768, 64, 64);
  }

  // final: part[z] = G2b[:, z*1024:(z+1)*1024] @ Wlt[:, z*1024:(z+1)*1024]^T
  gbt<128,128,2,2,3><<<dim3(1,1,32), 256, 0, stream>>>(G2b, 1024, 32768, Wlt, 1024, 32768,
                                                       nullptr, 0, part, 16384, 128, 1024);
  // out = leaky(sum_z part + bl)
  k_final2<<<dim3(64), 256, 0, stream>>>(part, bl, out);
}

// Round 7
// 262.959 us; speedup vs baseline: 6.8433x; 1.2298x over previous
//
#include <hip/hip_runtime.h>
#include <math.h>

#define KORD 3
#ifndef M_PI
#define M_PI 3.14159265358979323846
#endif

typedef __attribute__((ext_vector_type(8))) __bf16 bf16x8;
typedef __attribute__((ext_vector_type(4))) float  f32x4;

__device__ __forceinline__ float leaky_(float v){ return v >= 0.f ? v : 0.01f*v; }

__device__ __forceinline__ float tanh_fast(float x){
  float xc = fminf(fmaxf(x, -10.f), 10.f);
  float t = __expf(2.f*xc);
  return (t - 1.f) * __builtin_amdgcn_rcpf(t + 1.f);
}

__device__ __forceinline__ f32x4 mfma16(bf16x8 a, bf16x8 b, f32x4 c){
  return __builtin_amdgcn_mfma_f32_16x16x32_bf16(a, b, c, 0, 0, 0);
}

// ---------------- Chebyshev coefficients ----------------
__global__ void k_coe(const float* __restrict__ temp, float* __restrict__ coe){
  if (threadIdx.x == 0 && blockIdx.x == 0){
    for (int i = 0; i <= KORD; ++i){
      float acc = 0.f;
      for (int j = 0; j <= KORD; ++j){
        double th = ((double)(KORD - j) + 0.5) * M_PI / (double)(KORD + 1);
        float t = temp[j]; t = t > 0.f ? t : 0.f;
        acc += t * (float)cos((double)i * th);
      }
      coe[i] = acc * (2.f / (float)(KORD + 1));
    }
  }
}

// ---------------- f32 -> bf16 convert ----------------
__global__ __launch_bounds__(256) void k_cvt(const float* __restrict__ in,
                                             __bf16* __restrict__ out, int n){
  int i = blockIdx.x*256 + threadIdx.x;
  if (i < n) out[i] = (__bf16)in[i];
}

// ---------------- W1t[e][d] = W1[d][e] (bf16) ----------------
__global__ __launch_bounds__(256) void k_w1t(const float* __restrict__ W1,
                                             __bf16* __restrict__ W1t){
  int t = threadIdx.x;
  for (int i = 0; i < 16; ++i){
    int e4 = i*256 + t;
    int e = e4 >> 6, d = e4 & 63;
    W1t[e*64 + d] = (__bf16)W1[d*64 + e];
  }
}

// ---------------- Wlt[o][k] = Wl[k][o] (bf16), Wl: [32768][128] ----------------
__global__ __launch_bounds__(256) void k_wlt(const float* __restrict__ Wl,
                                             __bf16* __restrict__ Wlt){
  __shared__ float Ls[64][65];
  int k0 = blockIdx.x*64, o0 = blockIdx.y*64;
  int t = threadIdx.x;
  for (int i = 0; i < 16; ++i){
    int e = i*256 + t; int r = e >> 6, c = e & 63;
    Ls[r][c] = Wl[(size_t)(k0 + r)*128 + o0 + c];
  }
  __syncthreads();
  for (int i = 0; i < 16; ++i){
    int e = i*256 + t; int r = e >> 6, c = e & 63;
    Wlt[(size_t)(o0 + r)*32768 + k0 + c] = (__bf16)Ls[c][r];
  }
}

// ---------------- bsaT[m][n] = bsa[n][m] (f32) ----------------
__global__ __launch_bounds__(256) void k_bsat(const float* __restrict__ bsa,
                                              float* __restrict__ bsaT){
  __shared__ float Ls[64][65];
  int n0 = blockIdx.x*64, m0 = blockIdx.y*64;
  int t = threadIdx.x;
  for (int i = 0; i < 16; ++i){
    int e = i*256 + t; int r = e >> 6, c = e & 63;
    Ls[r][c] = bsa[(size_t)(n0 + r)*512 + m0 + c];
  }
  __syncthreads();
  for (int i = 0; i < 16; ++i){
    int e = i*256 + t; int r = e >> 6, c = e & 63;
    bsaT[(size_t)(m0 + r)*512 + n0 + c] = Ls[c][r];
  }
}

// ---------------- embed both layouts: Ht[j][n] and Hnd[cs][n][d] ----------------
__global__ __launch_bounds__(256) void k_embed2(const float* __restrict__ x,
    const float* __restrict__ Wp, const float* __restrict__ bp,
    __bf16* __restrict__ Ht, __bf16* __restrict__ Hnd){
  __shared__ float Ls[64][65];
  int cs = blockIdx.x, n0 = blockIdx.y*64;
  int t = threadIdx.x;
  for (int i = 0; i < 16; ++i){
    int e = i*256 + t; int d = e >> 6, nn = e & 63;
    float v = x[cs*512 + n0 + nn]*Wp[d] + bp[d];
    Ls[d][nn] = v;
    Ht[(size_t)(cs*64 + d)*512 + n0 + nn] = (__bf16)v;
  }
  __syncthreads();
  for (int i = 0; i < 16; ++i){
    int e = i*256 + t; int nn = e >> 6, d = e & 63;
    Hnd[((size_t)cs*512 + n0 + nn)*64 + d] = (__bf16)Ls[d][nn];
  }
}

// ---------------- combo: Gnd[cs][n][d] = c0/2*H + c1*T1 + c2*T2 + c3*T3 + SX (transposed) ----------------
__global__ __launch_bounds__(256) void k_combo(const __bf16* __restrict__ Ht,
    const __bf16* __restrict__ T1t, const __bf16* __restrict__ T2t,
    const __bf16* __restrict__ T3t, const __bf16* __restrict__ SXt,
    const float* __restrict__ coe, __bf16* __restrict__ Gnd){
  __shared__ float Ls[64][65];
  int cs = blockIdx.x, n0 = blockIdx.y*64;
  int t = threadIdx.x;
  float c0 = coe[0]*0.5f, c1 = coe[1], c2 = coe[2], c3 = coe[3];
  for (int i = 0; i < 16; ++i){
    int e = i*256 + t; int d = e >> 6, nn = e & 63;
    size_t idx = (size_t)(cs*64 + d)*512 + n0 + nn;
    Ls[d][nn] = c0*(float)Ht[idx] + c1*(float)T1t[idx] + c2*(float)T2t[idx]
              + c3*(float)T3t[idx] + (float)SXt[idx];
  }
  __syncthreads();
  for (int i = 0; i < 16; ++i){
    int e = i*256 + t; int nn = e >> 6, d = e & 63;
    Gnd[((size_t)cs*512 + n0 + nn)*64 + d] = (__bf16)Ls[d][nn];
  }
}

// ---------------- MFMA GEMM: C[z] = A[z] * B[z]^T (+epilogue) ----------------
// EPI: 0 = bf16 out; 1 = bf16 out 2*acc - Z; 2 = bf16 out tanh_fast(acc + Ef[row*512+col]);
//      3 = f32 out;  5 = bf16 out leaky(acc + Ef[col])
template<int BM, int BN, int WM, int WN, int EPI>
__global__ __launch_bounds__(256) void gbt(
    const __bf16* __restrict__ A, size_t aB, int lda,
    const __bf16* __restrict__ B, size_t bB, int ldb,
    const void*  __restrict__ E, size_t eB,
    void* __restrict__ C, size_t cB, int ldc, int K){
  constexpr int WTM = BM/WM, WTN = BN/WN;
  constexpr int FM = WTM/16, FN = WTN/16;
  constexpr int LDK = 72;
  __shared__ __bf16 As[BM*LDK];
  __shared__ __bf16 Bs[BN*LDK];
  const int tid = threadIdx.x;
  const int wave = tid >> 6, lane = tid & 63;
  const int wm = wave % WM, wn = wave / WM;
  const int m0 = blockIdx.x*BM, n0 = blockIdx.y*BN;
  const int z = blockIdx.z;
  const __bf16* Ab = A + (size_t)z*aB + (size_t)m0*lda;
  const __bf16* Bb = B + (size_t)z*bB + (size_t)n0*ldb;
  f32x4 acc[FM][FN] = {};
  for (int k0 = 0; k0 < K; k0 += 64){
    __syncthreads();
    constexpr int AIT = BM*64/(256*8);
#pragma unroll
    for (int i = 0; i < AIT; ++i){
      int e = i*256 + tid; int r = e >> 3, c = (e & 7)*8;
      *(float4*)&As[r*LDK + c] = *(const float4*)&Ab[(size_t)r*lda + k0 + c];
    }
    constexpr int BIT = BN*64/(256*8);
#pragma unroll
    for (int i = 0; i < BIT; ++i){
      int e = i*256 + tid; int r = e >> 3, c = (e & 7)*8;
      *(float4*)&Bs[r*LDK + c] = *(const float4*)&Bb[(size_t)r*ldb + k0 + c];
    }
    __syncthreads();
#pragma unroll
    for (int ks = 0; ks < 2; ++ks){
      bf16x8 af[FM], bfr[FN];
      const int ko = ks*32 + (lane >> 4)*8;
#pragma unroll
      for (int i = 0; i < FM; ++i)
        af[i] = *(const bf16x8*)&As[(wm*WTM + i*16 + (lane & 15))*LDK + ko];
#pragma unroll
      for (int j = 0; j < FN; ++j)
        bfr[j] = *(const bf16x8*)&Bs[(wn*WTN + j*16 + (lane & 15))*LDK + ko];
#pragma unroll
      for (int i = 0; i < FM; ++i)
#pragma unroll
        for (int j = 0; j < FN; ++j)
          acc[i][j] = mfma16(af[i], bfr[j], acc[i][j]);
    }
  }
  __bf16* Cb = (__bf16*)C + (size_t)z*cB;
  float*  Cf = (float*)C  + (size_t)z*cB;
  const __bf16* Zb = (const __bf16*)E + (size_t)z*eB;
  const float*  Ef = (const float*)E;
  const int lr = (lane >> 4)*4, lc = lane & 15;
#pragma unroll
  for (int i = 0; i < FM; ++i){
    int row = m0 + wm*WTM + i*16 + lr;
#pragma unroll
    for (int j = 0; j < FN; ++j){
      int col = n0 + wn*WTN + j*16 + lc;
#pragma unroll
      for (int r = 0; r < 4; ++r){
        float v = acc[i][j][r];
        size_t idx = (size_t)(row + r)*ldc + col;
        if (EPI == 0){ Cb[idx] = (__bf16)v; }
        else if (EPI == 1){ Cb[idx] = (__bf16)(2.f*v - (float)Zb[idx]); }
        else if (EPI == 2){ Cb[idx] = (__bf16)tanh_fast(v + Ef[(size_t)(row + r)*512 + col]); }
        else if (EPI == 3){ Cf[idx] = v; }
        else if (EPI == 5){ float tt = v + Ef[col]; Cb[idx] = (__bf16)(tt >= 0.f ? tt : 0.01f*tt); }
      }
    }
  }
}

// ---------------- softmax rows of 512, bf16 in-place ----------------
__global__ __launch_bounds__(256) void k_softmax(__bf16* __restrict__ S){
  int row  = blockIdx.x*4 + (threadIdx.x >> 6);
  int lane = threadIdx.x & 63;
  __bf16* p = S + (size_t)row*512;
  bf16x8 v = ((bf16x8*)p)[lane];
  float f[8];
#pragma unroll
  for (int j = 0; j < 8; ++j) f[j] = (float)v[j];
  float mx = f[0];
#pragma unroll
  for (int j = 1; j < 8; ++j) mx = fmaxf(mx, f[j]);
#pragma unroll
  for (int m = 1; m < 64; m <<= 1) mx = fmaxf(mx, __shfl_xor(mx, m, 64));
  float s = 0.f;
#pragma unroll
  for (int j = 0; j < 8; ++j){ f[j] = __expf(f[j] - mx); s += f[j]; }
#pragma unroll
  for (int m = 1; m < 64; m <<= 1) s += __shfl_xor(s, m, 64);
  float r = 1.f / s;
#pragma unroll
  for (int j = 0; j < 8; ++j) v[j] = (__bf16)(f[j]*r);
  ((bf16x8*)p)[lane] = v;
}

// ---------------- reduce 128 K-partials + bias + leaky ----------------
__global__ __launch_bounds__(256) void k_final2(
    const float* __restrict__ part, const float* __restrict__ bl,
    float* __restrict__ out){
  int idx = blockIdx.x*256 + threadIdx.x;
  int o = idx & 127;
  float acc = bl[o];
#pragma unroll 8
  for (int p = 0; p < 128; ++p) acc += part[(size_t)p*16384 + idx];
  out[idx] = leaky_(acc);
}

extern "C" void kernel_launch(void* const* d_in, const int* in_sizes, int n_in,
                              void* d_out, int out_size, void* d_ws, size_t ws_size,
                              hipStream_t stream){
  const float* x    = (const float*)d_in[0];
  const float* adj  = (const float*)d_in[1];
  const float* Wp   = (const float*)d_in[2];
  const float* bp   = (const float*)d_in[3];
  const float* Ksa  = (const float*)d_in[4];
  const float* Vsa  = (const float*)d_in[5];
  const float* bsa  = (const float*)d_in[6];
  const float* temp = (const float*)d_in[7];
  const float* W1   = (const float*)d_in[8];
  const float* b1   = (const float*)d_in[9];
  const float* Wl   = (const float*)d_in[10];
  const float* bl   = (const float*)d_in[11];
  float* out = (float*)d_out;

  // ---- workspace carve-up (bytes), chunk-adaptive ----
  char* ws = (char*)d_ws;
  size_t off = 0;
  auto alloc = [&](size_t bytes){ void* p = ws + off; off += (bytes + 255) & ~(size_t)255; return p; };
  float*  coe  = (float*)alloc(64);
  __bf16* G2b  = (__bf16*)alloc((size_t)128*32768*2);   // 8.4 MB
  __bf16* Wlt  = (__bf16*)alloc((size_t)128*32768*2);   // 8.4 MB
  float*  part = (float*)alloc((size_t)128*16384*4);    // 8.4 MB
  float*  bsaT = (float*)alloc((size_t)512*512*4);      // 1 MB
  __bf16* adjb = (__bf16*)alloc((size_t)512*512*2);
  __bf16* Ksab = (__bf16*)alloc((size_t)512*512*2);
  __bf16* Vsab = (__bf16*)alloc((size_t)512*512*2);
  __bf16* W1t  = (__bf16*)alloc((size_t)64*64*2);
  const size_t fixedOff = off;

  // per-slice: 8 bf16 [64x512] bufs (512KB) + Pt (512KB) + Sb (512KB)
  int CH = 128;
  while (CH > 2){
    size_t need = fixedOff + (size_t)CH*(8*65536 + 2*524288) + 65536;
    if (need <= ws_size) break;
    CH >>= 1;
  }
  __bf16* Ht   = (__bf16*)alloc((size_t)CH*65536);
  __bf16* T1t  = (__bf16*)alloc((size_t)CH*65536);
  __bf16* T2t  = (__bf16*)alloc((size_t)CH*65536);
  __bf16* T3t  = (__bf16*)alloc((size_t)CH*65536);
  __bf16* KXnd = (__bf16*)alloc((size_t)CH*65536);
  __bf16* Hnd  = (__bf16*)alloc((size_t)CH*65536);
  __bf16* SXt  = (__bf16*)alloc((size_t)CH*65536);
  __bf16* Gnd  = (__bf16*)alloc((size_t)CH*65536);
  __bf16* Pt   = (__bf16*)alloc((size_t)CH*524288);
  __bf16* Sb   = (__bf16*)alloc((size_t)CH*524288);

  // preprocessing
  k_coe<<<1, 64, 0, stream>>>(temp, coe);
  k_cvt<<<1024, 256, 0, stream>>>(adj, adjb, 512*512);
  k_cvt<<<1024, 256, 0, stream>>>(Ksa, Ksab, 512*512);
  k_cvt<<<1024, 256, 0, stream>>>(Vsa, Vsab, 512*512);
  k_w1t<<<1, 256, 0, stream>>>(W1, W1t);
  k_wlt<<<dim3(512,2), 256, 0, stream>>>(Wl, Wlt);
  k_bsat<<<dim3(8,8), 256, 0, stream>>>(bsa, bsaT);

  for (int s0 = 0; s0 < 128; s0 += CH){
    // embed both layouts
    k_embed2<<<dim3(CH,8), 256, 0, stream>>>(x + (size_t)s0*512, Wp, bp, Ht, Hnd);
    // Chebyshev (j-major), 64-row tiles for occupancy:
    gbt<64,128,2,2,0><<<dim3(CH,4,1), 256, 0, stream>>>(Ht, 0, 512, adjb, 0, 512, nullptr, 0, T1t, 0, 512, 512);
    gbt<64,128,2,2,1><<<dim3(CH,4,1), 256, 0, stream>>>(T1t, 0, 512, adjb, 0, 512, Ht, 0, T2t, 0, 512, 512);
    gbt<64,128,2,2,1><<<dim3(CH,4,1), 256, 0, stream>>>(T2t, 0, 512, adjb, 0, 512, T1t, 0, T3t, 0, 512, 512);
    // KXnd[cs][m][d] = Ksa @ H
    gbt<64,64,2,2,0><<<dim3(8,1,CH), 256, 0, stream>>>(Ksab, 0, 512, Ht, 32768, 512,
                                                       nullptr, 0, KXnd, 32768, 64, 512);
    // Pt[cs][c][m] = tanh(KXnd[cs]*Hnd[cs]^T + bsaT)  (K=64, bf16 out)
    gbt<128,128,2,2,2><<<dim3(4,4,CH), 256, 0, stream>>>(KXnd, 32768, 64, Hnd, 32768, 64,
                                                         bsaT, 0, Pt, 262144, 512, 64);
    // Sb[cs] = Vsa * Pt[cs]^T  (K=512, bf16 out)
    gbt<128,128,2,2,0><<<dim3(4,4,CH), 256, 0, stream>>>(Vsab, 0, 512, Pt, 262144, 512,
                                                         nullptr, 0, Sb, 262144, 512, 512);
    // softmax rows, bf16 in-place
    k_softmax<<<dim3(CH*128), 256, 0, stream>>>(Sb);
    // SXt[cs*64+d][n'] = sum_m Ht[d][m]*SA[n'][m]
    gbt<64,64,2,2,0><<<dim3(1,8,CH), 256, 0, stream>>>(Ht, 32768, 512, Sb, 262144, 512,
                                                       nullptr, 0, SXt, 32768, 512, 512);
    // Gnd = transpose(c0/2*Ht + c1*T1t + c2*T2t + c3*T3t + SXt)
    k_combo<<<dim3(CH,8), 256, 0, stream>>>(Ht, T1t, T2t, T3t, SXt, coe, Gnd);
    // G2b[s0+cs][n*64+e] = bf16(leaky(Gnd[cs]*W1t^T + b1))
    gbt<64,64,2,2,5><<<dim3(8,1,CH), 256, 0, stream>>>(Gnd, 32768, 64, W1t, 0, 64,
                                                       b1, 0, G2b + (size_t)s0*32768, 32768, 64, 64);
  }

  // final: part[z] = G2b[:, z*256:(z+1)*256] @ Wlt[:, z*256:(z+1)*256]^T  (f32 partials)
  gbt<128,128,2,2,3><<<dim3(1,1,128), 256, 0, stream>>>(G2b, 256, 32768, Wlt, 256, 32768,
                                                        nullptr, 0, part, 16384, 128, 256);
  // out = leaky(sum_z part + bl)
  k_final2<<<dim3(64), 256, 0, stream>>>(part, bl, out);
}

// Round 8
// 261.917 us; speedup vs baseline: 6.8705x; 1.0040x over previous
//
#include <hip/hip_runtime.h>
#include <math.h>

#define KORD 3
#ifndef M_PI
#define M_PI 3.14159265358979323846
#endif

typedef __attribute__((ext_vector_type(8))) __bf16 bf16x8;
typedef __attribute__((ext_vector_type(4))) float  f32x4;

__device__ __forceinline__ float leaky_(float v){ return v >= 0.f ? v : 0.01f*v; }

__device__ __forceinline__ float tanh_fast(float x){
  float xc = fminf(fmaxf(x, -10.f), 10.f);
  float t = __expf(2.f*xc);
  return (t - 1.f) * __builtin_amdgcn_rcpf(t + 1.f);
}

__device__ __forceinline__ f32x4 mfma16(bf16x8 a, bf16x8 b, f32x4 c){
  return __builtin_amdgcn_mfma_f32_16x16x32_bf16(a, b, c, 0, 0, 0);
}

// ---------------- Chebyshev coefficients ----------------
__global__ void k_coe(const float* __restrict__ temp, float* __restrict__ coe){
  if (threadIdx.x == 0 && blockIdx.x == 0){
    for (int i = 0; i <= KORD; ++i){
      float acc = 0.f;
      for (int j = 0; j <= KORD; ++j){
        double th = ((double)(KORD - j) + 0.5) * M_PI / (double)(KORD + 1);
        float t = temp[j]; t = t > 0.f ? t : 0.f;
        acc += t * (float)cos((double)i * th);
      }
      coe[i] = acc * (2.f / (float)(KORD + 1));
    }
  }
}

// ---------------- f32 -> bf16 convert ----------------
__global__ __launch_bounds__(256) void k_cvt(const float* __restrict__ in,
                                             __bf16* __restrict__ out, int n){
  int i = blockIdx.x*256 + threadIdx.x;
  if (i < n) out[i] = (__bf16)in[i];
}

// ---------------- W1t[e][d] = W1[d][e] (bf16) ----------------
__global__ __launch_bounds__(256) void k_w1t(const float* __restrict__ W1,
                                             __bf16* __restrict__ W1t){
  int t = threadIdx.x;
  for (int i = 0; i < 16; ++i){
    int e4 = i*256 + t;
    int e = e4 >> 6, d = e4 & 63;
    W1t[e*64 + d] = (__bf16)W1[d*64 + e];
  }
}

// ---------------- Wlt[o][k] = Wl[k][o] (bf16), Wl: [32768][128] ----------------
__global__ __launch_bounds__(256) void k_wlt(const float* __restrict__ Wl,
                                             __bf16* __restrict__ Wlt){
  __shared__ float Ls[64][65];
  int k0 = blockIdx.x*64, o0 = blockIdx.y*64;
  int t = threadIdx.x;
  for (int i = 0; i < 16; ++i){
    int e = i*256 + t; int r = e >> 6, c = e & 63;
    Ls[r][c] = Wl[(size_t)(k0 + r)*128 + o0 + c];
  }
  __syncthreads();
  for (int i = 0; i < 16; ++i){
    int e = i*256 + t; int r = e >> 6, c = e & 63;
    Wlt[(size_t)(o0 + r)*32768 + k0 + c] = (__bf16)Ls[c][r];
  }
}

// ---------------- bsaT[m][n] = bsa[n][m] (f32) ----------------
__global__ __launch_bounds__(256) void k_bsat(const float* __restrict__ bsa,
                                              float* __restrict__ bsaT){
  __shared__ float Ls[64][65];
  int n0 = blockIdx.x*64, m0 = blockIdx.y*64;
  int t = threadIdx.x;
  for (int i = 0; i < 16; ++i){
    int e = i*256 + t; int r = e >> 6, c = e & 63;
    Ls[r][c] = bsa[(size_t)(n0 + r)*512 + m0 + c];
  }
  __syncthreads();
  for (int i = 0; i < 16; ++i){
    int e = i*256 + t; int r = e >> 6, c = e & 63;
    bsaT[(size_t)(m0 + r)*512 + n0 + c] = Ls[c][r];
  }
}

// ---------------- embed both layouts: Ht[j][n] and Hnd[cs][n][d] ----------------
__global__ __launch_bounds__(256) void k_embed2(const float* __restrict__ x,
    const float* __restrict__ Wp, const float* __restrict__ bp,
    __bf16* __restrict__ Ht, __bf16* __restrict__ Hnd){
  __shared__ float Ls[64][65];
  int cs = blockIdx.x, n0 = blockIdx.y*64;
  int t = threadIdx.x;
  for (int i = 0; i < 16; ++i){
    int e = i*256 + t; int d = e >> 6, nn = e & 63;
    float v = x[cs*512 + n0 + nn]*Wp[d] + bp[d];
    Ls[d][nn] = v;
    Ht[(size_t)(cs*64 + d)*512 + n0 + nn] = (__bf16)v;
  }
  __syncthreads();
  for (int i = 0; i < 16; ++i){
    int e = i*256 + t; int nn = e >> 6, d = e & 63;
    Hnd[((size_t)cs*512 + n0 + nn)*64 + d] = (__bf16)Ls[d][nn];
  }
}

// ---------------- combo: Gnd[cs][n][d] = c0/2*H + c1*T1 + c2*T2 + c3*T3 + SX ----------------
__global__ __launch_bounds__(256) void k_combo(const __bf16* __restrict__ Ht,
    const __bf16* __restrict__ T1t, const __bf16* __restrict__ T2t,
    const __bf16* __restrict__ T3t, const __bf16* __restrict__ SXt,
    const float* __restrict__ coe, __bf16* __restrict__ Gnd){
  __shared__ float Ls[64][65];
  int cs = blockIdx.x, n0 = blockIdx.y*64;
  int t = threadIdx.x;
  float c0 = coe[0]*0.5f, c1 = coe[1], c2 = coe[2], c3 = coe[3];
  for (int i = 0; i < 16; ++i){
    int e = i*256 + t; int d = e >> 6, nn = e & 63;
    size_t idx = (size_t)(cs*64 + d)*512 + n0 + nn;
    Ls[d][nn] = c0*(float)Ht[idx] + c1*(float)T1t[idx] + c2*(float)T2t[idx]
              + c3*(float)T3t[idx] + (float)SXt[idx];
  }
  __syncthreads();
  for (int i = 0; i < 16; ++i){
    int e = i*256 + t; int nn = e >> 6, d = e & 63;
    Gnd[((size_t)cs*512 + n0 + nn)*64 + d] = (__bf16)Ls[d][nn];
  }
}

// ---------------- MFMA GEMM: C[z] = A[z] * B[z]^T (+epilogue) ----------------
// EPI: 0 bf16 out; 1 bf16 2v-Z; 2 bf16 tanh_fast(v+Ef[row*512+col]) REPACK;
//      3 f32 out; 5 bf16 leaky(v+Ef[col]); 6 bf16 exp(v)+rowsum atomics REPACK;
//      7 bf16 v*rcp(Ef[z*eB+col])
template<int BM, int BN, int WM, int WN, int EPI, bool SWZ>
__global__ __launch_bounds__(256) void gbt(
    const __bf16* __restrict__ A, size_t aB, int lda,
    const __bf16* __restrict__ B, size_t bB, int ldb,
    const void*  __restrict__ E, size_t eB,
    void* __restrict__ C, size_t cB, int ldc, int K, int gx, int gy){
  constexpr int WTM = BM/WM, WTN = BN/WN;
  constexpr int FM = WTM/16, FN = WTN/16;
  constexpr int LDK = 72;
  constexpr bool RPK = (EPI == 2 || EPI == 6);
  __shared__ __bf16 As[BM*LDK];
  __shared__ __bf16 Bs[BN*LDK];
  const int tid = threadIdx.x;
  const int wave = tid >> 6, lane = tid & 63;
  const int wm = wave % WM, wn = wave / WM;
  int bx, by, bz;
  if (SWZ){
    // all gx*gy tiles of one slice land on one XCD (slices striped across XCDs)
    int id = blockIdx.x;
    int xcd = id & 7, j = id >> 3;
    int tiles = gx*gy;
    int tile = j % tiles, sin = j / tiles;
    bz = xcd + 8*sin; bx = tile % gx; by = tile / gx;
  } else { bx = blockIdx.x; by = blockIdx.y; bz = blockIdx.z; }
  const int m0 = bx*BM, n0 = by*BN;
  const __bf16* Ab = A + (size_t)bz*aB + (size_t)m0*lda;
  const __bf16* Bb = B + (size_t)bz*bB + (size_t)n0*ldb;
  f32x4 acc[FM][FN] = {};
  for (int k0 = 0; k0 < K; k0 += 64){
    __syncthreads();
    constexpr int AIT = BM*64/(256*8);
#pragma unroll
    for (int i = 0; i < AIT; ++i){
      int e = i*256 + tid; int r = e >> 3, c = (e & 7)*8;
      *(float4*)&As[r*LDK + c] = *(const float4*)&Ab[(size_t)r*lda + k0 + c];
    }
    constexpr int BIT = BN*64/(256*8);
#pragma unroll
    for (int i = 0; i < BIT; ++i){
      int e = i*256 + tid; int r = e >> 3, c = (e & 7)*8;
      *(float4*)&Bs[r*LDK + c] = *(const float4*)&Bb[(size_t)r*ldb + k0 + c];
    }
    __syncthreads();
#pragma unroll
    for (int ks = 0; ks < 2; ++ks){
      bf16x8 af[FM], bfr[FN];
      const int ko = ks*32 + (lane >> 4)*8;
#pragma unroll
      for (int i = 0; i < FM; ++i)
        af[i] = *(const bf16x8*)&As[(wm*WTM + i*16 + (lane & 15))*LDK + ko];
#pragma unroll
      for (int j = 0; j < FN; ++j)
        bfr[j] = *(const bf16x8*)&Bs[(wn*WTN + j*16 + (lane & 15))*LDK + ko];
#pragma unroll
      for (int i = 0; i < FM; ++i)
#pragma unroll
        for (int j = 0; j < FN; ++j)
          acc[i][j] = mfma16(af[i], bfr[j], acc[i][j]);
    }
  }
  const int lr = (lane >> 4)*4, lc = lane & 15;
  if constexpr (RPK){
    // BM==BN==128, WM==WN==2 assumed.
    __bf16* Cb = (__bf16*)C + (size_t)bz*cB;
    if constexpr (EPI == 6){
      float* rs = (float*)E + (size_t)bz*eB;
#pragma unroll
      for (int i = 0; i < FM; ++i)
#pragma unroll
        for (int r = 0; r < 4; ++r){
          float sum = 0.f;
#pragma unroll
          for (int j = 0; j < FN; ++j) sum += __expf(fminf(acc[i][j][r], 30.f));
#pragma unroll
          for (int m = 1; m < 16; m <<= 1) sum += __shfl_xor(sum, m, 64);
          if ((lane & 15) == 0) atomicAdd(&rs[m0 + wm*WTM + i*16 + lr + r], sum);
        }
    }
#pragma unroll
    for (int p = 0; p < 2; ++p){
      __syncthreads();
      if (wn == p){
#pragma unroll
        for (int i = 0; i < FM; ++i)
#pragma unroll
          for (int j = 0; j < FN; ++j)
#pragma unroll
            for (int r = 0; r < 4; ++r){
              float v = acc[i][j][r];
              if constexpr (EPI == 2)
                v = tanh_fast(v + ((const float*)E)[(size_t)(m0 + wm*64 + i*16 + lr + r)*512
                                                    + (n0 + wn*64 + j*16 + lc)]);
              else
                v = __expf(fminf(v, 30.f));
              As[(wm*64 + i*16 + lr + r)*68 + j*16 + lc] = (__bf16)v;
            }
      }
      __syncthreads();
#pragma unroll
      for (int k = 0; k < 4; ++k){
        int q = k*256 + tid; int row = q >> 3, ch = q & 7;
        bf16x8 v8 = *(const bf16x8*)&As[row*68 + ch*8];
        *(bf16x8*)&Cb[(size_t)(m0 + row)*ldc + (n0 + p*64 + ch*8)] = v8;
      }
    }
    return;
  }
  __bf16* Cb = (__bf16*)C + (size_t)bz*cB;
  float*  Cf = (float*)C  + (size_t)bz*cB;
  const __bf16* Zb = (const __bf16*)E + (size_t)bz*eB;
  const float*  Ef = (const float*)E;
#pragma unroll
  for (int i = 0; i < FM; ++i){
    int row = m0 + wm*WTM + i*16 + lr;
#pragma unroll
    for (int j = 0; j < FN; ++j){
      int col = n0 + wn*WTN + j*16 + lc;
#pragma unroll
      for (int r = 0; r < 4; ++r){
        float v = acc[i][j][r];
        size_t idx = (size_t)(row + r)*ldc + col;
        if (EPI == 0){ Cb[idx] = (__bf16)v; }
        else if (EPI == 1){ Cb[idx] = (__bf16)(2.f*v - (float)Zb[idx]); }
        else if (EPI == 3){ Cf[idx] = v; }
        else if (EPI == 5){ float tt = v + Ef[col]; Cb[idx] = (__bf16)(tt >= 0.f ? tt : 0.01f*tt); }
        else if (EPI == 7){ Cb[idx] = (__bf16)(v * __builtin_amdgcn_rcpf(Ef[(size_t)bz*eB + col])); }
      }
    }
  }
}

// ---------------- reduce 128 K-partials + bias + leaky ----------------
__global__ __launch_bounds__(256) void k_final2(
    const float* __restrict__ part, const float* __restrict__ bl,
    float* __restrict__ out){
  int idx = blockIdx.x*256 + threadIdx.x;
  int o = idx & 127;
  float acc = bl[o];
#pragma unroll 8
  for (int p = 0; p < 128; ++p) acc += part[(size_t)p*16384 + idx];
  out[idx] = leaky_(acc);
}

extern "C" void kernel_launch(void* const* d_in, const int* in_sizes, int n_in,
                              void* d_out, int out_size, void* d_ws, size_t ws_size,
                              hipStream_t stream){
  const float* x    = (const float*)d_in[0];
  const float* adj  = (const float*)d_in[1];
  const float* Wp   = (const float*)d_in[2];
  const float* bp   = (const float*)d_in[3];
  const float* Ksa  = (const float*)d_in[4];
  const float* Vsa  = (const float*)d_in[5];
  const float* bsa  = (const float*)d_in[6];
  const float* temp = (const float*)d_in[7];
  const float* W1   = (const float*)d_in[8];
  const float* b1   = (const float*)d_in[9];
  const float* Wl   = (const float*)d_in[10];
  const float* bl   = (const float*)d_in[11];
  float* out = (float*)d_out;

  // ---- workspace carve-up (bytes), chunk-adaptive ----
  char* ws = (char*)d_ws;
  size_t off = 0;
  auto alloc = [&](size_t bytes){ void* p = ws + off; off += (bytes + 255) & ~(size_t)255; return p; };
  float*  coe  = (float*)alloc(64);
  __bf16* G2b  = (__bf16*)alloc((size_t)128*32768*2);   // 8.4 MB
  __bf16* Wlt  = (__bf16*)alloc((size_t)128*32768*2);   // 8.4 MB
  float*  part = (float*)alloc((size_t)128*16384*4);    // 8.4 MB
  float*  bsaT = (float*)alloc((size_t)512*512*4);      // 1 MB
  __bf16* adjb = (__bf16*)alloc((size_t)512*512*2);
  __bf16* Ksab = (__bf16*)alloc((size_t)512*512*2);
  __bf16* Vsab = (__bf16*)alloc((size_t)512*512*2);
  __bf16* W1t  = (__bf16*)alloc((size_t)64*64*2);
  const size_t fixedOff = off;

  // per-slice: 8 bf16 [64x512] bufs + Pt + Sb (512KB each) + rowsum (2KB)
  int CH = 128;
  while (CH > 2){
    size_t need = fixedOff + (size_t)CH*(8*65536 + 2*524288 + 2048) + 65536;
    if (need <= ws_size) break;
    CH >>= 1;
  }
  __bf16* Ht   = (__bf16*)alloc((size_t)CH*65536);
  __bf16* T1t  = (__bf16*)alloc((size_t)CH*65536);
  __bf16* T2t  = (__bf16*)alloc((size_t)CH*65536);
  __bf16* T3t  = (__bf16*)alloc((size_t)CH*65536);
  __bf16* KXnd = (__bf16*)alloc((size_t)CH*65536);
  __bf16* Hnd  = (__bf16*)alloc((size_t)CH*65536);
  __bf16* SXt  = (__bf16*)alloc((size_t)CH*65536);
  __bf16* Gnd  = (__bf16*)alloc((size_t)CH*65536);
  __bf16* Pt   = (__bf16*)alloc((size_t)CH*524288);
  __bf16* Sb   = (__bf16*)alloc((size_t)CH*524288);
  float*  rowsum = (float*)alloc((size_t)CH*512*4);

  const bool swz = (CH % 8) == 0;

  // preprocessing
  k_coe<<<1, 64, 0, stream>>>(temp, coe);
  k_cvt<<<1024, 256, 0, stream>>>(adj, adjb, 512*512);
  k_cvt<<<1024, 256, 0, stream>>>(Ksa, Ksab, 512*512);
  k_cvt<<<1024, 256, 0, stream>>>(Vsa, Vsab, 512*512);
  k_w1t<<<1, 256, 0, stream>>>(W1, W1t);
  k_wlt<<<dim3(512,2), 256, 0, stream>>>(Wl, Wlt);
  k_bsat<<<dim3(8,8), 256, 0, stream>>>(bsa, bsaT);

  for (int s0 = 0; s0 < 128; s0 += CH){
    // embed both layouts
    k_embed2<<<dim3(CH,8), 256, 0, stream>>>(x + (size_t)s0*512, Wp, bp, Ht, Hnd);
    // Chebyshev (j-major), 64-row tiles:
    gbt<64,128,2,2,0,false><<<dim3(CH,4,1), 256, 0, stream>>>(Ht, 0, 512, adjb, 0, 512, nullptr, 0, T1t, 0, 512, 512, 0, 0);
    gbt<64,128,2,2,1,false><<<dim3(CH,4,1), 256, 0, stream>>>(T1t, 0, 512, adjb, 0, 512, Ht, 0, T2t, 0, 512, 512, 0, 0);
    gbt<64,128,2,2,1,false><<<dim3(CH,4,1), 256, 0, stream>>>(T2t, 0, 512, adjb, 0, 512, T1t, 0, T3t, 0, 512, 512, 0, 0);
    // KXnd[cs][m][d] = Ksa @ H
    gbt<64,64,2,2,0,false><<<dim3(8,1,CH), 256, 0, stream>>>(Ksab, 0, 512, Ht, 32768, 512,
                                                             nullptr, 0, KXnd, 32768, 64, 512, 0, 0);
    // Pt[cs][c][m] = tanh(KXnd*Hnd^T + bsaT), repack-coalesced
    if (swz)
      gbt<128,128,2,2,2,true><<<dim3(16*CH), 256, 0, stream>>>(KXnd, 32768, 64, Hnd, 32768, 64,
                                                               bsaT, 0, Pt, 262144, 512, 64, 4, 4);
    else
      gbt<128,128,2,2,2,false><<<dim3(4,4,CH), 256, 0, stream>>>(KXnd, 32768, 64, Hnd, 32768, 64,
                                                                 bsaT, 0, Pt, 262144, 512, 64, 0, 0);
    // rowsum = 0
    hipMemsetAsync(rowsum, 0, (size_t)CH*512*4, stream);
    // Sb[cs] = exp(Vsa * Pt^T), rowsum atomics, repack-coalesced
    if (swz)
      gbt<128,128,2,2,6,true><<<dim3(16*CH), 256, 0, stream>>>(Vsab, 0, 512, Pt, 262144, 512,
                                                               rowsum, 512, Sb, 262144, 512, 512, 4, 4);
    else
      gbt<128,128,2,2,6,false><<<dim3(4,4,CH), 256, 0, stream>>>(Vsab, 0, 512, Pt, 262144, 512,
                                                                 rowsum, 512, Sb, 262144, 512, 512, 0, 0);
    // SXt[cs*64+d][n'] = (sum_m Ht[d][m]*expS[n'][m]) * rcp(rowsum[n'])
    gbt<64,64,2,2,7,false><<<dim3(1,8,CH), 256, 0, stream>>>(Ht, 32768, 512, Sb, 262144, 512,
                                                             rowsum, 512, SXt, 32768, 512, 512, 0, 0);
    // Gnd = transpose(c0/2*Ht + c1*T1t + c2*T2t + c3*T3t + SXt)
    k_combo<<<dim3(CH,8), 256, 0, stream>>>(Ht, T1t, T2t, T3t, SXt, coe, Gnd);
    // G2b = bf16(leaky(Gnd*W1t^T + b1))
    gbt<64,64,2,2,5,false><<<dim3(8,1,CH), 256, 0, stream>>>(Gnd, 32768, 64, W1t, 0, 64,
                                                             b1, 0, G2b + (size_t)s0*32768, 32768, 64, 64, 0, 0);
  }

  // final: part[z] = G2b[:, z*256:(z+1)*256] @ Wlt[:, z*256:(z+1)*256]^T
  gbt<128,128,2,2,3,false><<<dim3(1,1,128), 256, 0, stream>>>(G2b, 256, 32768, Wlt, 256, 32768,
                                                              nullptr, 0, part, 16384, 128, 256, 0, 0);
  // out = leaky(sum_z part + bl)
  k_final2<<<dim3(64), 256, 0, stream>>>(part, bl, out);
}